// Round 4
// baseline (596.621 us; speedup 1.0000x reference)
//
#include <hip/hip_runtime.h>
#include <hip/hip_fp16.h>

// Problem constants
static constexpr int kN = 50000;      // nodes per side
static constexpr int kE = 800000;     // edges per side
static constexpr int kG = 1024;       // graphs per batch
static constexpr int kEMB = 128;
static constexpr int kGH = 256;
static constexpr int kEH = 256;
static constexpr int kOUT = 128;
static constexpr int kHID = 512;
static constexpr int kNB = (kN + 255) / 256;   // 196 scan chunks per side

typedef __attribute__((ext_vector_type(8))) _Float16 half8v;
typedef __attribute__((ext_vector_type(4))) _Float16 half4v;
typedef __attribute__((ext_vector_type(4))) float floatx4;
typedef __attribute__((ext_vector_type(2))) float floatx2;

// NOTE (R6): cross-XCD plain-data handoff through grid.sync() gave stale reads.
// Phase boundaries are separate dispatches.
// NOTE (R7): device atomics execute memory-side; each dirties a 64B line.
// NOTE (R12): atomic floor is OP-COUNT (~21 ops/ns) — line padding is neutral.
// NOTE (R8): rank trick — counting atomic's return value = edge's rank in dst.
// NOTE (R10): lookback scan regressed (serial polling); BN=256 gemm2 regressed
// (VGPR/occupancy). NOTE (R11): heterogeneous role-merged grids regressed.
// NOTE (R2): fp8 hs rows 659->616us; absmax unchanged (mean-pool washes quant).
// NOTE (R3): conv1 16-lane groups + DPP reduce 616->596us; conv1 off top-5.
// rank now top at 70us = atomic op floor (1.6M ops at 22.9/ns, VALU 0.6%,
// HBM 11%) — confirmed unattackable without algorithm change; single stream
// forbids overlap. This revision: ushort col_idx/rankb (halve scatter's
// random-store line footprint across non-coherent XCD L2s) + split poolfc
// into pool + gemm32 (kill 512MB of per-block fcW L2 re-reads).

// fp8 fixed scale: |hs| <~ 0.2 typ; x128 keeps values in e4m3 normal range
// (min normal 2^-6) with ~17x headroom to OCP max 448.
#define HS_SCALE 128.0f
#define HS_INV   (1.0f / 128.0f)

__device__ inline void acc_fp8x4(unsigned int w, float& a0, float& a1, float& a2, float& a3) {
    floatx2 lo = __builtin_amdgcn_cvt_pk_f32_fp8(w, false);
    floatx2 hi = __builtin_amdgcn_cvt_pk_f32_fp8(w, true);
    a0 += lo[0]; a1 += lo[1]; a2 += hi[0]; a3 += hi[1];
}

// 16-lane group sum via DPP row_ror rotations (1,2,4,8): every lane of each
// 16-lane row ends with the full group sum. VALU-pipe only — no LDS traffic.
__device__ inline float grp16_reduce(float v) {
    int x;
    x = __builtin_amdgcn_update_dpp(0, __float_as_int(v), 0x121, 0xF, 0xF, true);
    v += __int_as_float(x);
    x = __builtin_amdgcn_update_dpp(0, __float_as_int(v), 0x122, 0xF, 0xF, true);
    v += __int_as_float(x);
    x = __builtin_amdgcn_update_dpp(0, __float_as_int(v), 0x124, 0xF, 0xF, true);
    v += __int_as_float(x);
    x = __builtin_amdgcn_update_dpp(0, __float_as_int(v), 0x128, 0xF, 0xF, true);
    v += __int_as_float(x);
    return v;
}

// ---------------------------------------------------------------------------
// prep: w2t = fp16(gW2^T) (blocks 0..255), M11 = atom_emb@gW1 (blocks 256..266)
// ---------------------------------------------------------------------------
__global__ void prep_kernel(const float* __restrict__ atom_emb, const float* __restrict__ gW1,
                            const float* __restrict__ gW2,
                            float* __restrict__ M11, _Float16* __restrict__ w2t) {
    int i = blockIdx.x * 256 + threadIdx.x;
    if (blockIdx.x < 256) {
        int k = i >> 8, n = i & 255;
        w2t[(size_t)n * kGH + k] = (_Float16)gW2[(size_t)k * kGH + n];
    } else {
        int j = i - 65536;
        if (j < 11 * kGH) {
            int r = j >> 8, c = j & 255;
            float s = 0.f;
            for (int k = 0; k < kEMB; k++) s += atom_emb[r * kEMB + k] * gW1[k * kGH + c];
            M11[j] = s;
        }
    }
}

// ---------------------------------------------------------------------------
// Rank pass: one returning atomic per edge (op-count floor, R12-measured).
// rank < max in-degree (~50) -> ushort.
// ---------------------------------------------------------------------------
__global__ void rank_kernel(const int* __restrict__ ei1, const int* __restrict__ ei2,
                            int* __restrict__ counts, unsigned short* __restrict__ rankb) {
    int side = blockIdx.y;
    const int* dst = (side ? ei2 : ei1) + kE;
    int i = blockIdx.x * blockDim.x + threadIdx.x;
    if (i >= kE) return;
    rankb[(size_t)side * kE + i] = (unsigned short)atomicAdd(&counts[side * kN + dst[i]], 1);
}

// Per-chunk sums (196 chunks per side)
__global__ void bsum_kernel(const int* __restrict__ counts, int* __restrict__ bsum) {
    int side = blockIdx.y;
    const int* c = counts + side * kN;
    int i = blockIdx.x * 256 + threadIdx.x;
    int v = (i < kN) ? c[i] : 0;
    #pragma unroll
    for (int o = 32; o; o >>= 1) v += __shfl_down(v, o);
    __shared__ int ws[4];
    if ((threadIdx.x & 63) == 0) ws[threadIdx.x >> 6] = v;
    __syncthreads();
    if (threadIdx.x == 0) bsum[side * kNB + blockIdx.x] = ws[0] + ws[1] + ws[2] + ws[3];
}

// Exclusive scan of the chunk sums (one block per side)
__global__ void bscan_kernel(const int* __restrict__ bsum, int* __restrict__ boff) {
    int side = blockIdx.x;
    __shared__ int s[256];
    int t = threadIdx.x;
    int v = (t < kNB) ? bsum[side * kNB + t] : 0;
    s[t] = v;
    __syncthreads();
    for (int o = 1; o < 256; o <<= 1) {
        int u = (t >= o) ? s[t - o] : 0;
        __syncthreads();
        s[t] += u;
        __syncthreads();
    }
    if (t < kNB) boff[side * kNB + t] = s[t] - v;   // exclusive
}

// Final: local inclusive scan per chunk + chunk offset -> row_ptr.
// Fused: dinv = rsqrt(deg+1) and xd[v] = (x[v], bits(dinv[v])).
__global__ void scanf_kernel(const int* __restrict__ counts, const int* __restrict__ boff,
                             int* __restrict__ row_ptr, float* __restrict__ dinv,
                             int2* __restrict__ xd,
                             const int* __restrict__ x1, const int* __restrict__ x2) {
    int side = blockIdx.y;
    const int* c = counts + side * kN;
    int* rp = row_ptr + side * (kN + 1);
    int t = threadIdx.x;
    int i = blockIdx.x * 256 + t;
    __shared__ int s[256];
    int v = (i < kN) ? c[i] : 0;
    s[t] = v;
    __syncthreads();
    for (int o = 1; o < 256; o <<= 1) {
        int u = (t >= o) ? s[t - o] : 0;
        __syncthreads();
        s[t] += u;
        __syncthreads();
    }
    if (i < kN) {
        rp[i + 1] = boff[side * kNB + blockIdx.x] + s[t];
        float dv = rsqrtf((float)(v + 1));           // +1 self-loop
        dinv[side * kN + i] = dv;
        const int* x = side ? x2 : x1;
        xd[side * kN + i] = make_int2(x[i], __float_as_int(dv));
    }
    if (i == 0) rp[0] = 0;
}

// ---------------------------------------------------------------------------
// CSR scatter: plain stores, zero atomics (pos = row_ptr[d] + rank[e]).
// ushort col_idx (node id < 65536): halves the random-store line footprint
// -> less partial-dirty-line writeback across the 8 non-coherent XCD L2s.
// ---------------------------------------------------------------------------
__global__ void scatter_kernel(const int* __restrict__ ei1, const int* __restrict__ ei2,
                               const int* __restrict__ row_ptr,
                               const unsigned short* __restrict__ rank,
                               unsigned short* __restrict__ col_idx) {
    int side = blockIdx.y;
    const int* ei = side ? ei2 : ei1;
    const int* rp = row_ptr + side * (kN + 1);
    int i = blockIdx.x * blockDim.x + threadIdx.x;
    if (i >= kE) return;
    int s = ei[i];           // src
    int d = ei[kE + i];      // dst
    int pos = rp[d] + (int)rank[(size_t)side * kE + i];
    col_idx[(size_t)side * kE + pos] = (unsigned short)s;
}

// ---------------------------------------------------------------------------
// Conv1 combine, 16-lane groups (4 nodes/wave), DPP reduce, zero LDS ops.
// h2[v] = relu(dv*(dv*M11[x[v]] + sum_t wt[t]*M11[t]) + b1)
// kN = 50000 = 3125 * 16 exactly -> no bounds checks, all lanes always active
// (required for exec-safe DPP).
// ---------------------------------------------------------------------------
__global__ void conv1_combine_kernel(const int2* __restrict__ xd,
                                     const int* __restrict__ row_ptr,
                                     const unsigned short* __restrict__ col_idx,
                                     const float* __restrict__ M11,
                                     const float* __restrict__ bias,
                                     _Float16* __restrict__ out) {
    int side = blockIdx.y;
    const int2* xdb = xd + (size_t)side * kN;
    const int* rp = row_ptr + side * (kN + 1);
    const unsigned short* ci = col_idx + (size_t)side * kE;
    _Float16* ob = out + (size_t)side * kN * kGH;

    int tid = threadIdx.x;
    int sub = tid & 15;                 // lane within 16-lane group
    int v = blockIdx.x * 16 + (tid >> 4);   // node per group (exact: 3125*16=50000)

    int e0 = rp[v], e1 = rp[v + 1];
    float wt[11];
    #pragma unroll
    for (int t = 0; t < 11; t++) wt[t] = 0.f;
    for (int base = e0; base < e1; base += 16) {
        int e = base + sub;
        int xs = 15; float ds = 0.f;
        if (e < e1) {
            int2 t = xdb[(int)ci[e]];
            xs = t.x; ds = __int_as_float(t.y);
        }
        #pragma unroll
        for (int t = 0; t < 11; t++) wt[t] += (xs == t) ? ds : 0.f;
    }
    #pragma unroll
    for (int t = 0; t < 11; t++) wt[t] = grp16_reduce(wt[t]);

    int2 xv = xdb[v];
    float dv = __int_as_float(xv.y);
    #pragma unroll
    for (int q = 0; q < 4; q++) {
        int c = q * 64 + sub * 4;       // coalesced per group: 16 lanes x 16B
        float4 bia = *(const float4*)(bias + c);
        float4 m = *(const float4*)(M11 + xv.x * kGH + c);
        float4 acc = make_float4(dv * m.x, dv * m.y, dv * m.z, dv * m.w);
        #pragma unroll
        for (int t = 0; t < 11; t++) {
            float w = wt[t];
            float4 mt = *(const float4*)(M11 + t * kGH + c);
            acc.x += w * mt.x; acc.y += w * mt.y;
            acc.z += w * mt.z; acc.w += w * mt.w;
        }
        half4v o;
        o[0] = (_Float16)fmaxf(dv * acc.x + bia.x, 0.f);
        o[1] = (_Float16)fmaxf(dv * acc.y + bia.y, 0.f);
        o[2] = (_Float16)fmaxf(dv * acc.z + bia.z, 0.f);
        o[3] = (_Float16)fmaxf(dv * acc.w + bia.w, 0.f);
        *(half4v*)(ob + (size_t)v * kGH + c) = o;
    }
}

// ---------------------------------------------------------------------------
// Conv2 GEMM via MFMA f16, LDS-tiled: hs = fp8(HS_SCALE * dinv ⊙ (h2 @ W2))
// BM=128, BN=128, BK=64 (R9-measured config). 4 waves (2x2); wave = 64x64.
// ---------------------------------------------------------------------------
__launch_bounds__(256)
__global__ void gemm2_mfma_kernel(const _Float16* __restrict__ A,
                                  const _Float16* __restrict__ Bt,
                                  const float* __restrict__ dinv,
                                  unsigned char* __restrict__ C) {
    __shared__ _Float16 As[128][72];
    __shared__ _Float16 Bs[128][72];

    int side = blockIdx.z;
    const _Float16* Ab = A + (size_t)side * kN * kGH;
    const float* db = dinv + (size_t)side * kN;
    unsigned char* Cb = C + (size_t)side * kN * kGH;

    int tid = threadIdx.x;
    int wave = tid >> 6, lane = tid & 63;
    int quad = lane >> 4, r = lane & 15;
    int wm = wave >> 1, wn = wave & 1;
    int row0 = blockIdx.x * 128;
    int col0 = blockIdx.y * 128;

    floatx4 acc[4][4];
    #pragma unroll
    for (int i = 0; i < 4; i++)
        #pragma unroll
        for (int j = 0; j < 4; j++) acc[i][j] = (floatx4){0.f, 0.f, 0.f, 0.f};

    for (int k0 = 0; k0 < kGH; k0 += 64) {
        #pragma unroll
        for (int u = 0; u < 4; u++) {
            int idx = tid + u * 256;           // 0..1023
            int row = idx >> 3;                // 0..127
            int seg = (idx & 7) * 8;           // 0..56
            int gr = row0 + row;
            if (gr >= kN) gr = kN - 1;
            *(half8v*)&As[row][seg] = *(const half8v*)(Ab + (size_t)gr * kGH + k0 + seg);
            *(half8v*)&Bs[row][seg] = *(const half8v*)(Bt + (size_t)(col0 + row) * kGH + k0 + seg);
        }
        __syncthreads();
        #pragma unroll
        for (int ks = 0; ks < 2; ks++) {
            half8v af[4], bf[4];
            #pragma unroll
            for (int mt = 0; mt < 4; mt++)
                af[mt] = *(const half8v*)&As[wm * 64 + mt * 16 + r][ks * 32 + quad * 8];
            #pragma unroll
            for (int nt = 0; nt < 4; nt++)
                bf[nt] = *(const half8v*)&Bs[wn * 64 + nt * 16 + r][ks * 32 + quad * 8];
            #pragma unroll
            for (int mt = 0; mt < 4; mt++)
                #pragma unroll
                for (int nt = 0; nt < 4; nt++)
                    acc[mt][nt] = __builtin_amdgcn_mfma_f32_16x16x32_f16(af[mt], bf[nt],
                                                                         acc[mt][nt], 0, 0, 0);
        }
        __syncthreads();
    }

    // Epilogue: C/D layout col = r, row = quad*4 + i.  fp8 e4m3 store, x128.
    #pragma unroll
    for (int mt = 0; mt < 4; mt++) {
        #pragma unroll
        for (int i = 0; i < 4; i++) {
            int grow = row0 + wm * 64 + mt * 16 + quad * 4 + i;
            if (grow >= kN) continue;
            float rsq = db[grow] * HS_SCALE;
            #pragma unroll
            for (int nt = 0; nt < 4; nt++) {
                int gcol = col0 + wn * 64 + nt * 16 + r;
                float q = acc[mt][nt][i] * rsq;
                Cb[(size_t)grow * kGH + gcol] =
                    (unsigned char)__builtin_amdgcn_cvt_pk_fp8_f32(q, q, 0, false);
            }
        }
    }
}

// ---------------------------------------------------------------------------
// Conv2 aggregate: h4[v] = relu(dinv[v]*(hs[v] + sum_s hs[s])/HS_SCALE + b2)
// hs fp8 e4m3: halves the random-gather bytes vs the fp16 110us floor.
// Per gathered row: 64 lanes x 4B = 256B contiguous. NT store on h4 (not
// re-read this dispatch; avoid L2 write-allocate evicting gather-hot lines).
// ---------------------------------------------------------------------------
__global__ void aggregate2_kernel(const unsigned char* __restrict__ hs, const float* __restrict__ dinv,
                                  const int* __restrict__ row_ptr,
                                  const unsigned short* __restrict__ col_idx,
                                  const float* __restrict__ bias, _Float16* __restrict__ out) {
    int side = blockIdx.y;
    const unsigned char* hb = hs + (size_t)side * kN * kGH;
    const float* dv_ = dinv + side * kN;
    const int* rp = row_ptr + side * (kN + 1);
    const unsigned short* ci = col_idx + (size_t)side * kE;
    _Float16* ob = out + (size_t)side * kN * kGH;

    int wave = threadIdx.x >> 6;
    int lane = threadIdx.x & 63;
    int v = blockIdx.x * 4 + wave;
    if (v >= kN) return;
    int c = lane * 4;
    float4 bia = *(const float4*)(bias + c);
    float dv = dv_[v];
    float a0 = 0.f, a1 = 0.f, a2 = 0.f, a3 = 0.f;
    acc_fp8x4(*(const unsigned int*)(hb + (size_t)v * kGH + c), a0, a1, a2, a3);  // self-loop
    int e0 = rp[v], e1 = rp[v + 1];
    for (int base = e0; base < e1; base += 64) {
        int cnt = min(64, e1 - base);
        int idxl = (base + lane < e1) ? (int)ci[base + lane] : 0;
        int j = 0;
        for (; j + 16 <= cnt; j += 16) {
            unsigned int w[16];
            #pragma unroll
            for (int u = 0; u < 16; u++)
                w[u] = *(const unsigned int*)(hb + (size_t)__shfl(idxl, j + u) * kGH + c);
            #pragma unroll
            for (int u = 0; u < 16; u++) acc_fp8x4(w[u], a0, a1, a2, a3);
        }
        for (; j + 8 <= cnt; j += 8) {
            unsigned int w[8];
            #pragma unroll
            for (int u = 0; u < 8; u++)
                w[u] = *(const unsigned int*)(hb + (size_t)__shfl(idxl, j + u) * kGH + c);
            #pragma unroll
            for (int u = 0; u < 8; u++) acc_fp8x4(w[u], a0, a1, a2, a3);
        }
        for (; j < cnt; j++)
            acc_fp8x4(*(const unsigned int*)(hb + (size_t)__shfl(idxl, j) * kGH + c),
                      a0, a1, a2, a3);
    }
    float f = dv * HS_INV;
    half4v o;
    o[0] = (_Float16)fmaxf(f * a0 + bia.x, 0.f);
    o[1] = (_Float16)fmaxf(f * a1 + bia.y, 0.f);
    o[2] = (_Float16)fmaxf(f * a2 + bia.z, 0.f);
    o[3] = (_Float16)fmaxf(f * a3 + bia.w, 0.f);
    __builtin_nontemporal_store(o, (half4v*)(ob + (size_t)v * kGH + c));
}

// ---------------------------------------------------------------------------
// Mean-pool only: pooled[g] = mean_{v in g}(h4[v])  (fc moved to gemm32 —
// poolfc's per-block fcW re-read was 512MB of L2 traffic).
// ---------------------------------------------------------------------------
__global__ void pool_kernel(const _Float16* __restrict__ h,
                            const int* __restrict__ batch1, const int* __restrict__ batch2,
                            float* __restrict__ pooled) {
    int side = blockIdx.y;
    const _Float16* hb = h + (size_t)side * kN * kGH;
    const int* batch = side ? batch2 : batch1;
    int g = blockIdx.x;
    int lo = 0, hi = kN;
    while (lo < hi) { int mid = (lo + hi) >> 1; if (batch[mid] < g) lo = mid + 1; else hi = mid; }
    int start = lo;
    lo = start; hi = kN;
    while (lo < hi) { int mid = (lo + hi) >> 1; if (batch[mid] < g + 1) lo = mid + 1; else hi = mid; }
    int end = lo;
    int c = threadIdx.x;  // 256
    float s = 0.f;
    for (int v = start; v < end; v++) s += (float)hb[(size_t)v * kGH + c];
    pooled[(size_t)(side * kG + g) * kGH + c] = s / fmaxf((float)(end - start), 1.0f);
}

// ---------------------------------------------------------------------------
// Generic tiled fp32 GEMM, BM=32 BN=64 (tail layers; 2x block count vs 64x64
// -> full CU coverage at M=1024/2048). K-order identical to 64-tile version.
// ---------------------------------------------------------------------------
__launch_bounds__(256)
__global__ void gemm32_kernel(const float* __restrict__ A, const float* __restrict__ B,
                              float* __restrict__ C, int M, int N, int K,
                              const float* __restrict__ bias, int relu) {
    __shared__ float As[16][32];
    __shared__ float Bs[16][64];
    int tid = threadIdx.x;
    int tx = tid & 15, ty = tid >> 4;
    int row0 = blockIdx.y * 32, col0 = blockIdx.x * 64;
    float acc[2][4] = {};
    for (int k0 = 0; k0 < K; k0 += 16) {
        {   // A tile 32x16, transposed into LDS (float2 per thread)
            int r = tid >> 3, seg = (tid & 7) * 2;
            int gr = row0 + r;
            float2 v = make_float2(0.f, 0.f);
            if (gr < M) v = *(const float2*)(A + (size_t)gr * K + k0 + seg);
            As[seg + 0][r] = v.x; As[seg + 1][r] = v.y;
        }
        {   // B tile 16x64
            int kr = tid >> 4, c4 = (tid & 15) * 4;
            float4 v = *(const float4*)(B + (size_t)(k0 + kr) * N + col0 + c4);
            *(float4*)&Bs[kr][c4] = v;
        }
        __syncthreads();
        #pragma unroll
        for (int k = 0; k < 16; k++) {
            float a[2], b[4];
            #pragma unroll
            for (int i = 0; i < 2; i++) a[i] = As[k][ty * 2 + i];
            #pragma unroll
            for (int j = 0; j < 4; j++) b[j] = Bs[k][tx * 4 + j];
            #pragma unroll
            for (int i = 0; i < 2; i++)
                #pragma unroll
                for (int j = 0; j < 4; j++)
                    acc[i][j] += a[i] * b[j];
        }
        __syncthreads();
    }
    #pragma unroll
    for (int i = 0; i < 2; i++) {
        int gr = row0 + ty * 2 + i;
        if (gr >= M) continue;
        #pragma unroll
        for (int j = 0; j < 4; j++) {
            int gc = col0 + tx * 4 + j;
            float v = acc[i][j];
            if (bias) v += bias[gc];
            if (relu) v = fmaxf(v, 0.f);
            C[(size_t)gr * N + gc] = v;
        }
    }
}

// ---------------------------------------------------------------------------
// eW1 GEMM with fused entity gather+relu on the A-load.
// ---------------------------------------------------------------------------
__launch_bounds__(256)
__global__ void gemm_entgather_kernel(const float* __restrict__ emb,
                                      const int* __restrict__ ent1, const int* __restrict__ ent2,
                                      const float* __restrict__ B, float* __restrict__ C,
                                      int N, const float* __restrict__ bias) {
    __shared__ float As[16][64];
    __shared__ float Bs[16][64];
    int tid = threadIdx.x;
    int tx = tid & 15, ty = tid >> 4;
    int row0 = blockIdx.y * 64, col0 = blockIdx.x * 64;
    float acc[4][4] = {};
    for (int k0 = 0; k0 < kEMB; k0 += 16) {
        {
            int r = tid >> 2, seg = tid & 3;
            int gr = row0 + r;                 // < 2G always
            int idx = (gr < kG) ? ent1[gr] : ent2[gr - kG];
            float4 v = *(const float4*)(emb + (size_t)idx * kEMB + k0 + seg * 4);
            As[seg * 4 + 0][r] = fmaxf(v.x, 0.f); As[seg * 4 + 1][r] = fmaxf(v.y, 0.f);
            As[seg * 4 + 2][r] = fmaxf(v.z, 0.f); As[seg * 4 + 3][r] = fmaxf(v.w, 0.f);
        }
        {
            int kr = tid >> 4, c4 = (tid & 15) * 4;
            float4 v = *(const float4*)(B + (size_t)(k0 + kr) * N + col0 + c4);
            *(float4*)&Bs[kr][c4] = v;
        }
        __syncthreads();
        #pragma unroll
        for (int k = 0; k < 16; k++) {
            float a[4], b[4];
            #pragma unroll
            for (int i = 0; i < 4; i++) a[i] = As[k][ty * 4 + i];
            #pragma unroll
            for (int j = 0; j < 4; j++) b[j] = Bs[k][tx * 4 + j];
            #pragma unroll
            for (int i = 0; i < 4; i++)
                #pragma unroll
                for (int j = 0; j < 4; j++)
                    acc[i][j] += a[i] * b[j];
        }
        __syncthreads();
    }
    #pragma unroll
    for (int i = 0; i < 4; i++) {
        int gr = row0 + ty * 4 + i;
        #pragma unroll
        for (int j = 0; j < 4; j++) {
            int gc = col0 + tx * 4 + j;
            C[(size_t)gr * N + gc] = fmaxf(acc[i][j] + bias[gc], 0.f);
        }
    }
}

// ---------------------------------------------------------------------------
// dW1 GEMM with fused egs computation on the A-load.
// ---------------------------------------------------------------------------
__launch_bounds__(256)
__global__ void gemm_egs_kernel(const float* __restrict__ gfc, const float* __restrict__ ento,
                                const float* __restrict__ B, float* __restrict__ C,
                                int N, const float* __restrict__ bias) {
    __shared__ float As[16][64];
    __shared__ float Bs[16][64];
    int tid = threadIdx.x;
    int tx = tid & 15, ty = tid >> 4;
    int row0 = blockIdx.y * 64, col0 = blockIdx.x * 64;
    float acc[4][4] = {};
    for (int k0 = 0; k0 < kHID; k0 += 16) {
        {
            int r = tid >> 2, seg = tid & 3;
            int gr = row0 + r;                 // < G always
            int k = k0 + seg * 4;
            float4 va, vb;
            if (k < kGH) {
                va = *(const float4*)(gfc + (size_t)gr * kGH + k);
                vb = *(const float4*)(gfc + (size_t)(gr + kG) * kGH + k);
            } else {
                va = *(const float4*)(ento + (size_t)gr * kEH + k - kGH);
                vb = *(const float4*)(ento + (size_t)(gr + kG) * kEH + k - kGH);
            }
            As[seg * 4 + 0][r] = fmaxf(va.x + vb.x, 0.f);
            As[seg * 4 + 1][r] = fmaxf(va.y + vb.y, 0.f);
            As[seg * 4 + 2][r] = fmaxf(va.z + vb.z, 0.f);
            As[seg * 4 + 3][r] = fmaxf(va.w + vb.w, 0.f);
        }
        {
            int kr = tid >> 4, c4 = (tid & 15) * 4;
            float4 v = *(const float4*)(B + (size_t)(k0 + kr) * N + col0 + c4);
            *(float4*)&Bs[kr][c4] = v;
        }
        __syncthreads();
        #pragma unroll
        for (int k = 0; k < 16; k++) {
            float a[4], b[4];
            #pragma unroll
            for (int i = 0; i < 4; i++) a[i] = As[k][ty * 4 + i];
            #pragma unroll
            for (int j = 0; j < 4; j++) b[j] = Bs[k][tx * 4 + j];
            #pragma unroll
            for (int i = 0; i < 4; i++)
                #pragma unroll
                for (int j = 0; j < 4; j++)
                    acc[i][j] += a[i] * b[j];
        }
        __syncthreads();
    }
    #pragma unroll
    for (int i = 0; i < 4; i++) {
        int gr = row0 + ty * 4 + i;
        #pragma unroll
        for (int j = 0; j < 4; j++) {
            int gc = col0 + tx * 4 + j;
            C[(size_t)gr * N + gc] = fmaxf(acc[i][j] + bias[gc], 0.f);
        }
    }
}

// ---------------------------------------------------------------------------
// Host launch
// ---------------------------------------------------------------------------
static inline char* carve(char*& p, size_t bytes) {
    char* r = p;
    p += (bytes + 255) & ~(size_t)255;
    return r;
}

extern "C" void kernel_launch(void* const* d_in, const int* in_sizes, int n_in,
                              void* d_out, int out_size, void* d_ws, size_t ws_size,
                              hipStream_t stream) {
    const int*   x1       = (const int*)d_in[0];
    const int*   ei1      = (const int*)d_in[1];
    const int*   ent1     = (const int*)d_in[2];
    const int*   batch1   = (const int*)d_in[3];
    const int*   x2       = (const int*)d_in[4];
    const int*   ei2      = (const int*)d_in[5];
    const int*   ent2     = (const int*)d_in[6];
    const int*   batch2   = (const int*)d_in[7];
    const float* atom_emb = (const float*)d_in[8];
    const float* gW1      = (const float*)d_in[9];
    const float* gb1      = (const float*)d_in[10];
    const float* gW2      = (const float*)d_in[11];
    const float* gb2      = (const float*)d_in[12];
    const float* fcW      = (const float*)d_in[13];
    const float* fcb      = (const float*)d_in[14];
    const float* ent_emb  = (const float*)d_in[15];
    const float* eW1      = (const float*)d_in[16];
    const float* eb1      = (const float*)d_in[17];
    const float* eW2      = (const float*)d_in[18];
    const float* eb2      = (const float*)d_in[19];
    const float* dW1      = (const float*)d_in[20];
    const float* db1      = (const float*)d_in[21];
    const float* dW2      = (const float*)d_in[22];
    const float* db2      = (const float*)d_in[23];
    const float* dW3      = (const float*)d_in[24];
    const float* db3      = (const float*)d_in[25];
    float* out = (float*)d_out;

    // Workspace carve; counts is the only zeroed span.
    char* p = (char*)d_ws;
    _Float16* h2_h   = (_Float16*)carve(p, (size_t)2 * kN * kGH * 2);  // also h4
    unsigned char* hs8 = (unsigned char*)carve(p, (size_t)2 * kN * kGH); // fp8 hs
    unsigned short* col_idx = (unsigned short*)carve(p, (size_t)2 * kE * 2);
    unsigned short* rankb   = (unsigned short*)carve(p, (size_t)2 * kE * 2);
    int*   row_ptr = (int*)  carve(p, (size_t)2 * (kN + 1) * 4);
    int*   counts  = (int*)  carve(p, (size_t)2 * kN * 4);
    float* dinv    = (float*)carve(p, (size_t)2 * kN * 4);
    int2*  xd      = (int2*) carve(p, (size_t)2 * kN * 8);
    int*   bsum    = (int*)  carve(p, (size_t)2 * kNB * 4);
    int*   boff    = (int*)  carve(p, (size_t)2 * kNB * 4);
    float* M11     = (float*)carve(p, 11 * kGH * 4);
    _Float16* w2t  = (_Float16*)carve(p, (size_t)kGH * kGH * 2);
    float* pooled  = (float*)carve(p, (size_t)2 * kG * kGH * 4);
    float* gfc     = (float*)carve(p, (size_t)2 * kG * kGH * 4);
    float* etmp    = (float*)carve(p, (size_t)2 * kG * kEH * 4);
    float* ento    = (float*)carve(p, (size_t)2 * kG * kEH * 4);
    float* dh1     = (float*)carve(p, (size_t)kG * kHID * 4);
    float* dh2     = (float*)carve(p, (size_t)kG * kHID * 4);

    // --- Graph structure + conv1 (kernel boundaries = safe grid barriers) ---
    hipMemsetAsync(counts, 0, (size_t)2 * kN * 4, stream);
    prep_kernel<<<267, 256, 0, stream>>>(atom_emb, gW1, gW2, M11, w2t);
    rank_kernel<<<dim3(kE / 256, 2), 256, 0, stream>>>(ei1, ei2, counts, rankb);
    bsum_kernel<<<dim3(kNB, 2), 256, 0, stream>>>(counts, bsum);
    bscan_kernel<<<2, 256, 0, stream>>>(bsum, boff);
    scanf_kernel<<<dim3(kNB, 2), 256, 0, stream>>>(counts, boff, row_ptr, dinv, xd, x1, x2);
    scatter_kernel<<<dim3(kE / 256, 2), 256, 0, stream>>>(ei1, ei2, row_ptr, rankb, col_idx);
    conv1_combine_kernel<<<dim3(kN / 16, 2), 256, 0, stream>>>(xd, row_ptr, col_idx,
                                                               M11, gb1, h2_h);

    // --- Conv2 GEMM (MFMA f16, BN=128): hs8 = fp8(128 * dinv ⊙ (h2 @ W2)) ---
    gemm2_mfma_kernel<<<dim3((kN + 127) / 128, kGH / 128, 2), 256, 0, stream>>>(h2_h, w2t,
                                                                                dinv, hs8);
    // --- Conv2 aggregate -> h4 (reuses h2 buffer) ---
    aggregate2_kernel<<<dim3((kN + 3) / 4, 2), 256, 0, stream>>>(hs8, dinv, row_ptr, col_idx,
                                                                 gb2, h2_h);
    // --- Mean-pool -> pooled [2G, GH], then fc via tiled GEMM -> gfc ---
    pool_kernel<<<dim3(kG, 2), 256, 0, stream>>>(h2_h, batch1, batch2, pooled);
    gemm32_kernel<<<dim3(kGH / 64, 2 * kG / 32), 256, 0, stream>>>(pooled, fcW, gfc,
                                                                   2 * kG, kGH, kGH, fcb, 0);

    // --- Entity encoders (gather+relu fused into eW1; eW2 on 32-row tiles) ---
    gemm_entgather_kernel<<<dim3(kEH / 64, 2 * kG / 64), 256, 0, stream>>>(ent_emb, ent1, ent2,
                                                                           eW1, etmp, kEH, eb1);
    gemm32_kernel<<<dim3(kEH / 64, 2 * kG / 32), 256, 0, stream>>>(etmp, eW2, ento,
                                                                   2 * kG, kEH, kEH, eb2, 1);
    // --- Decoder (egs fused into dW1; dW2/dW3 on 32-row tiles) ---
    gemm_egs_kernel<<<dim3(kHID / 64, kG / 64), 256, 0, stream>>>(gfc, ento, dW1, dh1,
                                                                  kHID, db1);
    gemm32_kernel<<<dim3(kHID / 64, kG / 32), 256, 0, stream>>>(dh1, dW2, dh2,
                                                                kG, kHID, kHID, db2, 1);
    gemm32_kernel<<<dim3(kOUT / 64, kG / 32), 256, 0, stream>>>(dh2, dW3, out,
                                                                kG, kOUT, kHID, db3, 0);
}

// Round 5
// 585.503 us; speedup vs baseline: 1.0190x; 1.0190x over previous
//
#include <hip/hip_runtime.h>
#include <hip/hip_fp16.h>

// Problem constants
static constexpr int kN = 50000;      // nodes per side
static constexpr int kE = 800000;     // edges per side
static constexpr int kG = 1024;       // graphs per batch
static constexpr int kEMB = 128;
static constexpr int kGH = 256;
static constexpr int kEH = 256;
static constexpr int kOUT = 128;
static constexpr int kHID = 512;
static constexpr int kNB = (kN + 255) / 256;   // 196 chunks per side
static constexpr int kMD = 64;        // ELL stride; deg ~ Poisson(16), P(deg>=64)~e^-125

typedef __attribute__((ext_vector_type(8))) _Float16 half8v;
typedef __attribute__((ext_vector_type(4))) _Float16 half4v;
typedef __attribute__((ext_vector_type(4))) float floatx4;
typedef __attribute__((ext_vector_type(2))) float floatx2;

// NOTE (R6): cross-XCD plain-data handoff through grid.sync() gave stale reads.
// Phase boundaries are separate dispatches.
// NOTE (R7): device atomics execute memory-side; each dirties a 64B line.
// NOTE (R12): atomic floor is OP-COUNT (~21 ops/ns) — line padding is neutral.
// NOTE (R8): rank trick — counting atomic's return value = edge's rank in dst.
// NOTE (R10): lookback scan regressed; (R11): role-merged grids regressed.
// NOTE (R2): fp8 hs rows 659->616us; absmax unchanged (mean-pool washes quant).
// NOTE (R3): conv1 16-lane groups + DPP reduce 616->596us.
// NOTE (R4): ushort col_idx + poolfc split = NEUTRAL (596us) — scatter is
// line-RMW op-bound, not byte-bound; fcW re-reads were L2-absorbed.
// This revision (R5): ELL-64 replaces CSR. rank's returning atomic IS the ELL
// slot -> col_ell[dst*64+rank]=src written in rank_kernel; scatter/bsum/bscan
// and the scanf scan are ELIMINATED. ELL stores cluster per dst row (2 lines)
// and hide under the 69us atomic floor.

// fp8 fixed scale: |hs| <~ 0.2 typ; x128 keeps values in e4m3 normal range.
#define HS_SCALE 128.0f
#define HS_INV   (1.0f / 128.0f)

__device__ inline void acc_fp8x4(unsigned int w, float& a0, float& a1, float& a2, float& a3) {
    floatx2 lo = __builtin_amdgcn_cvt_pk_f32_fp8(w, false);
    floatx2 hi = __builtin_amdgcn_cvt_pk_f32_fp8(w, true);
    a0 += lo[0]; a1 += lo[1]; a2 += hi[0]; a3 += hi[1];
}

// 16-lane group sum via DPP row_ror rotations (1,2,4,8): every lane of each
// 16-lane row ends with the full group sum. VALU-pipe only — no LDS traffic.
__device__ inline float grp16_reduce(float v) {
    int x;
    x = __builtin_amdgcn_update_dpp(0, __float_as_int(v), 0x121, 0xF, 0xF, true);
    v += __int_as_float(x);
    x = __builtin_amdgcn_update_dpp(0, __float_as_int(v), 0x122, 0xF, 0xF, true);
    v += __int_as_float(x);
    x = __builtin_amdgcn_update_dpp(0, __float_as_int(v), 0x124, 0xF, 0xF, true);
    v += __int_as_float(x);
    x = __builtin_amdgcn_update_dpp(0, __float_as_int(v), 0x128, 0xF, 0xF, true);
    v += __int_as_float(x);
    return v;
}

// ---------------------------------------------------------------------------
// prep: w2t = fp16(gW2^T) (blocks 0..255), M11 = atom_emb@gW1 (blocks 256..266)
// ---------------------------------------------------------------------------
__global__ void prep_kernel(const float* __restrict__ atom_emb, const float* __restrict__ gW1,
                            const float* __restrict__ gW2,
                            float* __restrict__ M11, _Float16* __restrict__ w2t) {
    int i = blockIdx.x * 256 + threadIdx.x;
    if (blockIdx.x < 256) {
        int k = i >> 8, n = i & 255;
        w2t[(size_t)n * kGH + k] = (_Float16)gW2[(size_t)k * kGH + n];
    } else {
        int j = i - 65536;
        if (j < 11 * kGH) {
            int r = j >> 8, c = j & 255;
            float s = 0.f;
            for (int k = 0; k < kEMB; k++) s += atom_emb[r * kEMB + k] * gW1[k * kGH + c];
            M11[j] = s;
        }
    }
}

// ---------------------------------------------------------------------------
// Rank+ELL pass: the returning atomic's value is the ELL slot. Direct store
// replaces the whole CSR scatter pipeline. At the atomic op floor; the
// clustered 2B stores (2 lines per dst row) hide under it.
// ---------------------------------------------------------------------------
__global__ void rank_ell_kernel(const int* __restrict__ ei1, const int* __restrict__ ei2,
                                int* __restrict__ counts, unsigned short* __restrict__ col_ell) {
    int side = blockIdx.y;
    const int* ei = side ? ei2 : ei1;
    int i = blockIdx.x * blockDim.x + threadIdx.x;
    if (i >= kE) return;
    int s = ei[i];           // src
    int d = ei[kE + i];      // dst
    int r = atomicAdd(&counts[side * kN + d], 1);
    if (r > kMD - 1) r = kMD - 1;   // unreachable (P~e^-125); memory-safety only
    col_ell[((size_t)side * kN + d) * kMD + r] = (unsigned short)s;
}

// deg -> dinv = rsqrt(deg+1); xd[v] = (x[v], bits(dinv[v])). No scan needed.
__global__ void dinvx_kernel(const int* __restrict__ counts, float* __restrict__ dinv,
                             int2* __restrict__ xd,
                             const int* __restrict__ x1, const int* __restrict__ x2) {
    int side = blockIdx.y;
    int i = blockIdx.x * 256 + threadIdx.x;
    if (i >= kN) return;
    int v = counts[side * kN + i];
    float dv = rsqrtf((float)(v + 1));           // +1 self-loop
    dinv[side * kN + i] = dv;
    const int* x = side ? x2 : x1;
    xd[side * kN + i] = make_int2(x[i], __float_as_int(dv));
}

// ---------------------------------------------------------------------------
// Conv1 combine, 16-lane groups (4 nodes/wave), DPP reduce, zero LDS ops.
// h2[v] = relu(dv*(dv*M11[x[v]] + sum_t wt[t]*M11[t]) + b1)
// ELL neighbor rows: col_ell[v*64 .. v*64+deg). kN = 3125*16 exactly ->
// no bounds checks, all lanes always active (required for exec-safe DPP).
// ---------------------------------------------------------------------------
__global__ void conv1_combine_kernel(const int2* __restrict__ xd,
                                     const int* __restrict__ counts,
                                     const unsigned short* __restrict__ col_ell,
                                     const float* __restrict__ M11,
                                     const float* __restrict__ bias,
                                     _Float16* __restrict__ out) {
    int side = blockIdx.y;
    const int2* xdb = xd + (size_t)side * kN;
    const int* deg = counts + side * kN;
    const unsigned short* ci = col_ell + (size_t)side * kN * kMD;
    _Float16* ob = out + (size_t)side * kN * kGH;

    int tid = threadIdx.x;
    int sub = tid & 15;                 // lane within 16-lane group
    int v = blockIdx.x * 16 + (tid >> 4);   // node per group (exact: 3125*16=50000)

    int cnt = min(deg[v], kMD);
    const unsigned short* cv = ci + (size_t)v * kMD;
    float wt[11];
    #pragma unroll
    for (int t = 0; t < 11; t++) wt[t] = 0.f;
    for (int base = 0; base < cnt; base += 16) {
        int e = base + sub;
        int xs = 15; float ds = 0.f;
        if (e < cnt) {
            int2 t = xdb[(int)cv[e]];
            xs = t.x; ds = __int_as_float(t.y);
        }
        #pragma unroll
        for (int t = 0; t < 11; t++) wt[t] += (xs == t) ? ds : 0.f;
    }
    #pragma unroll
    for (int t = 0; t < 11; t++) wt[t] = grp16_reduce(wt[t]);

    int2 xv = xdb[v];
    float dv = __int_as_float(xv.y);
    #pragma unroll
    for (int q = 0; q < 4; q++) {
        int c = q * 64 + sub * 4;       // coalesced per group: 16 lanes x 16B
        float4 bia = *(const float4*)(bias + c);
        float4 m = *(const float4*)(M11 + xv.x * kGH + c);
        float4 acc = make_float4(dv * m.x, dv * m.y, dv * m.z, dv * m.w);
        #pragma unroll
        for (int t = 0; t < 11; t++) {
            float w = wt[t];
            float4 mt = *(const float4*)(M11 + t * kGH + c);
            acc.x += w * mt.x; acc.y += w * mt.y;
            acc.z += w * mt.z; acc.w += w * mt.w;
        }
        half4v o;
        o[0] = (_Float16)fmaxf(dv * acc.x + bia.x, 0.f);
        o[1] = (_Float16)fmaxf(dv * acc.y + bia.y, 0.f);
        o[2] = (_Float16)fmaxf(dv * acc.z + bia.z, 0.f);
        o[3] = (_Float16)fmaxf(dv * acc.w + bia.w, 0.f);
        *(half4v*)(ob + (size_t)v * kGH + c) = o;
    }
}

// ---------------------------------------------------------------------------
// Conv2 GEMM via MFMA f16, LDS-tiled: hs = fp8(HS_SCALE * dinv ⊙ (h2 @ W2))
// BM=128, BN=128, BK=64 (R9-measured config). 4 waves (2x2); wave = 64x64.
// ---------------------------------------------------------------------------
__launch_bounds__(256)
__global__ void gemm2_mfma_kernel(const _Float16* __restrict__ A,
                                  const _Float16* __restrict__ Bt,
                                  const float* __restrict__ dinv,
                                  unsigned char* __restrict__ C) {
    __shared__ _Float16 As[128][72];
    __shared__ _Float16 Bs[128][72];

    int side = blockIdx.z;
    const _Float16* Ab = A + (size_t)side * kN * kGH;
    const float* db = dinv + (size_t)side * kN;
    unsigned char* Cb = C + (size_t)side * kN * kGH;

    int tid = threadIdx.x;
    int wave = tid >> 6, lane = tid & 63;
    int quad = lane >> 4, r = lane & 15;
    int wm = wave >> 1, wn = wave & 1;
    int row0 = blockIdx.x * 128;
    int col0 = blockIdx.y * 128;

    floatx4 acc[4][4];
    #pragma unroll
    for (int i = 0; i < 4; i++)
        #pragma unroll
        for (int j = 0; j < 4; j++) acc[i][j] = (floatx4){0.f, 0.f, 0.f, 0.f};

    for (int k0 = 0; k0 < kGH; k0 += 64) {
        #pragma unroll
        for (int u = 0; u < 4; u++) {
            int idx = tid + u * 256;           // 0..1023
            int row = idx >> 3;                // 0..127
            int seg = (idx & 7) * 8;           // 0..56
            int gr = row0 + row;
            if (gr >= kN) gr = kN - 1;
            *(half8v*)&As[row][seg] = *(const half8v*)(Ab + (size_t)gr * kGH + k0 + seg);
            *(half8v*)&Bs[row][seg] = *(const half8v*)(Bt + (size_t)(col0 + row) * kGH + k0 + seg);
        }
        __syncthreads();
        #pragma unroll
        for (int ks = 0; ks < 2; ks++) {
            half8v af[4], bf[4];
            #pragma unroll
            for (int mt = 0; mt < 4; mt++)
                af[mt] = *(const half8v*)&As[wm * 64 + mt * 16 + r][ks * 32 + quad * 8];
            #pragma unroll
            for (int nt = 0; nt < 4; nt++)
                bf[nt] = *(const half8v*)&Bs[wn * 64 + nt * 16 + r][ks * 32 + quad * 8];
            #pragma unroll
            for (int mt = 0; mt < 4; mt++)
                #pragma unroll
                for (int nt = 0; nt < 4; nt++)
                    acc[mt][nt] = __builtin_amdgcn_mfma_f32_16x16x32_f16(af[mt], bf[nt],
                                                                         acc[mt][nt], 0, 0, 0);
        }
        __syncthreads();
    }

    // Epilogue: C/D layout col = r, row = quad*4 + i.  fp8 e4m3 store, x128.
    #pragma unroll
    for (int mt = 0; mt < 4; mt++) {
        #pragma unroll
        for (int i = 0; i < 4; i++) {
            int grow = row0 + wm * 64 + mt * 16 + quad * 4 + i;
            if (grow >= kN) continue;
            float rsq = db[grow] * HS_SCALE;
            #pragma unroll
            for (int nt = 0; nt < 4; nt++) {
                int gcol = col0 + wn * 64 + nt * 16 + r;
                float q = acc[mt][nt][i] * rsq;
                Cb[(size_t)grow * kGH + gcol] =
                    (unsigned char)__builtin_amdgcn_cvt_pk_fp8_f32(q, q, 0, false);
            }
        }
    }
}

// ---------------------------------------------------------------------------
// Conv2 aggregate: h4[v] = relu(dinv[v]*(hs[v] + sum_s hs[s])/HS_SCALE + b2)
// hs fp8 e4m3. ELL row: cnt<=64 -> one gather round (lane's idxl covers all).
// NT store on h4 (not re-read this dispatch).
// ---------------------------------------------------------------------------
__global__ void aggregate2_kernel(const unsigned char* __restrict__ hs, const float* __restrict__ dinv,
                                  const int* __restrict__ counts,
                                  const unsigned short* __restrict__ col_ell,
                                  const float* __restrict__ bias, _Float16* __restrict__ out) {
    int side = blockIdx.y;
    const unsigned char* hb = hs + (size_t)side * kN * kGH;
    const float* dv_ = dinv + side * kN;
    const int* deg = counts + side * kN;
    const unsigned short* ci = col_ell + (size_t)side * kN * kMD;
    _Float16* ob = out + (size_t)side * kN * kGH;

    int wave = threadIdx.x >> 6;
    int lane = threadIdx.x & 63;
    int v = blockIdx.x * 4 + wave;
    if (v >= kN) return;
    int c = lane * 4;
    float4 bia = *(const float4*)(bias + c);
    float dv = dv_[v];
    float a0 = 0.f, a1 = 0.f, a2 = 0.f, a3 = 0.f;
    acc_fp8x4(*(const unsigned int*)(hb + (size_t)v * kGH + c), a0, a1, a2, a3);  // self-loop
    int cnt = min(deg[v], kMD);
    int idxl = (lane < cnt) ? (int)ci[(size_t)v * kMD + lane] : 0;
    int j = 0;
    for (; j + 16 <= cnt; j += 16) {
        unsigned int w[16];
        #pragma unroll
        for (int u = 0; u < 16; u++)
            w[u] = *(const unsigned int*)(hb + (size_t)__shfl(idxl, j + u) * kGH + c);
        #pragma unroll
        for (int u = 0; u < 16; u++) acc_fp8x4(w[u], a0, a1, a2, a3);
    }
    for (; j + 8 <= cnt; j += 8) {
        unsigned int w[8];
        #pragma unroll
        for (int u = 0; u < 8; u++)
            w[u] = *(const unsigned int*)(hb + (size_t)__shfl(idxl, j + u) * kGH + c);
        #pragma unroll
        for (int u = 0; u < 8; u++) acc_fp8x4(w[u], a0, a1, a2, a3);
    }
    for (; j < cnt; j++)
        acc_fp8x4(*(const unsigned int*)(hb + (size_t)__shfl(idxl, j) * kGH + c),
                  a0, a1, a2, a3);
    float f = dv * HS_INV;
    half4v o;
    o[0] = (_Float16)fmaxf(f * a0 + bia.x, 0.f);
    o[1] = (_Float16)fmaxf(f * a1 + bia.y, 0.f);
    o[2] = (_Float16)fmaxf(f * a2 + bia.z, 0.f);
    o[3] = (_Float16)fmaxf(f * a3 + bia.w, 0.f);
    __builtin_nontemporal_store(o, (half4v*)(ob + (size_t)v * kGH + c));
}

// ---------------------------------------------------------------------------
// Mean-pool only: pooled[g] = mean_{v in g}(h4[v])  (fc via gemm32)
// ---------------------------------------------------------------------------
__global__ void pool_kernel(const _Float16* __restrict__ h,
                            const int* __restrict__ batch1, const int* __restrict__ batch2,
                            float* __restrict__ pooled) {
    int side = blockIdx.y;
    const _Float16* hb = h + (size_t)side * kN * kGH;
    const int* batch = side ? batch2 : batch1;
    int g = blockIdx.x;
    int lo = 0, hi = kN;
    while (lo < hi) { int mid = (lo + hi) >> 1; if (batch[mid] < g) lo = mid + 1; else hi = mid; }
    int start = lo;
    lo = start; hi = kN;
    while (lo < hi) { int mid = (lo + hi) >> 1; if (batch[mid] < g + 1) lo = mid + 1; else hi = mid; }
    int end = lo;
    int c = threadIdx.x;  // 256
    float s = 0.f;
    for (int v = start; v < end; v++) s += (float)hb[(size_t)v * kGH + c];
    pooled[(size_t)(side * kG + g) * kGH + c] = s / fmaxf((float)(end - start), 1.0f);
}

// ---------------------------------------------------------------------------
// Generic tiled fp32 GEMM, BM=32 BN=64 (tail layers).
// ---------------------------------------------------------------------------
__launch_bounds__(256)
__global__ void gemm32_kernel(const float* __restrict__ A, const float* __restrict__ B,
                              float* __restrict__ C, int M, int N, int K,
                              const float* __restrict__ bias, int relu) {
    __shared__ float As[16][32];
    __shared__ float Bs[16][64];
    int tid = threadIdx.x;
    int tx = tid & 15, ty = tid >> 4;
    int row0 = blockIdx.y * 32, col0 = blockIdx.x * 64;
    float acc[2][4] = {};
    for (int k0 = 0; k0 < K; k0 += 16) {
        {   // A tile 32x16, transposed into LDS (float2 per thread)
            int r = tid >> 3, seg = (tid & 7) * 2;
            int gr = row0 + r;
            float2 v = make_float2(0.f, 0.f);
            if (gr < M) v = *(const float2*)(A + (size_t)gr * K + k0 + seg);
            As[seg + 0][r] = v.x; As[seg + 1][r] = v.y;
        }
        {   // B tile 16x64
            int kr = tid >> 4, c4 = (tid & 15) * 4;
            float4 v = *(const float4*)(B + (size_t)(k0 + kr) * N + col0 + c4);
            *(float4*)&Bs[kr][c4] = v;
        }
        __syncthreads();
        #pragma unroll
        for (int k = 0; k < 16; k++) {
            float a[2], b[4];
            #pragma unroll
            for (int i = 0; i < 2; i++) a[i] = As[k][ty * 2 + i];
            #pragma unroll
            for (int j = 0; j < 4; j++) b[j] = Bs[k][tx * 4 + j];
            #pragma unroll
            for (int i = 0; i < 2; i++)
                #pragma unroll
                for (int j = 0; j < 4; j++)
                    acc[i][j] += a[i] * b[j];
        }
        __syncthreads();
    }
    #pragma unroll
    for (int i = 0; i < 2; i++) {
        int gr = row0 + ty * 2 + i;
        if (gr >= M) continue;
        #pragma unroll
        for (int j = 0; j < 4; j++) {
            int gc = col0 + tx * 4 + j;
            float v = acc[i][j];
            if (bias) v += bias[gc];
            if (relu) v = fmaxf(v, 0.f);
            C[(size_t)gr * N + gc] = v;
        }
    }
}

// ---------------------------------------------------------------------------
// eW1 GEMM with fused entity gather+relu on the A-load.
// ---------------------------------------------------------------------------
__launch_bounds__(256)
__global__ void gemm_entgather_kernel(const float* __restrict__ emb,
                                      const int* __restrict__ ent1, const int* __restrict__ ent2,
                                      const float* __restrict__ B, float* __restrict__ C,
                                      int N, const float* __restrict__ bias) {
    __shared__ float As[16][64];
    __shared__ float Bs[16][64];
    int tid = threadIdx.x;
    int tx = tid & 15, ty = tid >> 4;
    int row0 = blockIdx.y * 64, col0 = blockIdx.x * 64;
    float acc[4][4] = {};
    for (int k0 = 0; k0 < kEMB; k0 += 16) {
        {
            int r = tid >> 2, seg = tid & 3;
            int gr = row0 + r;                 // < 2G always
            int idx = (gr < kG) ? ent1[gr] : ent2[gr - kG];
            float4 v = *(const float4*)(emb + (size_t)idx * kEMB + k0 + seg * 4);
            As[seg * 4 + 0][r] = fmaxf(v.x, 0.f); As[seg * 4 + 1][r] = fmaxf(v.y, 0.f);
            As[seg * 4 + 2][r] = fmaxf(v.z, 0.f); As[seg * 4 + 3][r] = fmaxf(v.w, 0.f);
        }
        {
            int kr = tid >> 4, c4 = (tid & 15) * 4;
            float4 v = *(const float4*)(B + (size_t)(k0 + kr) * N + col0 + c4);
            *(float4*)&Bs[kr][c4] = v;
        }
        __syncthreads();
        #pragma unroll
        for (int k = 0; k < 16; k++) {
            float a[4], b[4];
            #pragma unroll
            for (int i = 0; i < 4; i++) a[i] = As[k][ty * 4 + i];
            #pragma unroll
            for (int j = 0; j < 4; j++) b[j] = Bs[k][tx * 4 + j];
            #pragma unroll
            for (int i = 0; i < 4; i++)
                #pragma unroll
                for (int j = 0; j < 4; j++)
                    acc[i][j] += a[i] * b[j];
        }
        __syncthreads();
    }
    #pragma unroll
    for (int i = 0; i < 4; i++) {
        int gr = row0 + ty * 4 + i;
        #pragma unroll
        for (int j = 0; j < 4; j++) {
            int gc = col0 + tx * 4 + j;
            C[(size_t)gr * N + gc] = fmaxf(acc[i][j] + bias[gc], 0.f);
        }
    }
}

// ---------------------------------------------------------------------------
// dW1 GEMM with fused egs computation on the A-load.
// ---------------------------------------------------------------------------
__launch_bounds__(256)
__global__ void gemm_egs_kernel(const float* __restrict__ gfc, const float* __restrict__ ento,
                                const float* __restrict__ B, float* __restrict__ C,
                                int N, const float* __restrict__ bias) {
    __shared__ float As[16][64];
    __shared__ float Bs[16][64];
    int tid = threadIdx.x;
    int tx = tid & 15, ty = tid >> 4;
    int row0 = blockIdx.y * 64, col0 = blockIdx.x * 64;
    float acc[4][4] = {};
    for (int k0 = 0; k0 < kHID; k0 += 16) {
        {
            int r = tid >> 2, seg = tid & 3;
            int gr = row0 + r;                 // < G always
            int k = k0 + seg * 4;
            float4 va, vb;
            if (k < kGH) {
                va = *(const float4*)(gfc + (size_t)gr * kGH + k);
                vb = *(const float4*)(gfc + (size_t)(gr + kG) * kGH + k);
            } else {
                va = *(const float4*)(ento + (size_t)gr * kEH + k - kGH);
                vb = *(const float4*)(ento + (size_t)(gr + kG) * kEH + k - kGH);
            }
            As[seg * 4 + 0][r] = fmaxf(va.x + vb.x, 0.f);
            As[seg * 4 + 1][r] = fmaxf(va.y + vb.y, 0.f);
            As[seg * 4 + 2][r] = fmaxf(va.z + vb.z, 0.f);
            As[seg * 4 + 3][r] = fmaxf(va.w + vb.w, 0.f);
        }
        {
            int kr = tid >> 4, c4 = (tid & 15) * 4;
            float4 v = *(const float4*)(B + (size_t)(k0 + kr) * N + col0 + c4);
            *(float4*)&Bs[kr][c4] = v;
        }
        __syncthreads();
        #pragma unroll
        for (int k = 0; k < 16; k++) {
            float a[4], b[4];
            #pragma unroll
            for (int i = 0; i < 4; i++) a[i] = As[k][ty * 4 + i];
            #pragma unroll
            for (int j = 0; j < 4; j++) b[j] = Bs[k][tx * 4 + j];
            #pragma unroll
            for (int i = 0; i < 4; i++)
                #pragma unroll
                for (int j = 0; j < 4; j++)
                    acc[i][j] += a[i] * b[j];
        }
        __syncthreads();
    }
    #pragma unroll
    for (int i = 0; i < 4; i++) {
        int gr = row0 + ty * 4 + i;
        #pragma unroll
        for (int j = 0; j < 4; j++) {
            int gc = col0 + tx * 4 + j;
            C[(size_t)gr * N + gc] = fmaxf(acc[i][j] + bias[gc], 0.f);
        }
    }
}

// ---------------------------------------------------------------------------
// Host launch
// ---------------------------------------------------------------------------
static inline char* carve(char*& p, size_t bytes) {
    char* r = p;
    p += (bytes + 255) & ~(size_t)255;
    return r;
}

extern "C" void kernel_launch(void* const* d_in, const int* in_sizes, int n_in,
                              void* d_out, int out_size, void* d_ws, size_t ws_size,
                              hipStream_t stream) {
    const int*   x1       = (const int*)d_in[0];
    const int*   ei1      = (const int*)d_in[1];
    const int*   ent1     = (const int*)d_in[2];
    const int*   batch1   = (const int*)d_in[3];
    const int*   x2       = (const int*)d_in[4];
    const int*   ei2      = (const int*)d_in[5];
    const int*   ent2     = (const int*)d_in[6];
    const int*   batch2   = (const int*)d_in[7];
    const float* atom_emb = (const float*)d_in[8];
    const float* gW1      = (const float*)d_in[9];
    const float* gb1      = (const float*)d_in[10];
    const float* gW2      = (const float*)d_in[11];
    const float* gb2      = (const float*)d_in[12];
    const float* fcW      = (const float*)d_in[13];
    const float* fcb      = (const float*)d_in[14];
    const float* ent_emb  = (const float*)d_in[15];
    const float* eW1      = (const float*)d_in[16];
    const float* eb1      = (const float*)d_in[17];
    const float* eW2      = (const float*)d_in[18];
    const float* eb2      = (const float*)d_in[19];
    const float* dW1      = (const float*)d_in[20];
    const float* db1      = (const float*)d_in[21];
    const float* dW2      = (const float*)d_in[22];
    const float* db2      = (const float*)d_in[23];
    const float* dW3      = (const float*)d_in[24];
    const float* db3      = (const float*)d_in[25];
    float* out = (float*)d_out;

    // Workspace carve; counts is the only zeroed span.
    char* p = (char*)d_ws;
    _Float16* h2_h   = (_Float16*)carve(p, (size_t)2 * kN * kGH * 2);  // also h4
    unsigned char* hs8 = (unsigned char*)carve(p, (size_t)2 * kN * kGH); // fp8 hs
    unsigned short* col_ell = (unsigned short*)carve(p, (size_t)2 * kN * kMD * 2);
    int*   counts  = (int*)  carve(p, (size_t)2 * kN * 4);
    float* dinv    = (float*)carve(p, (size_t)2 * kN * 4);
    int2*  xd      = (int2*) carve(p, (size_t)2 * kN * 8);
    float* M11     = (float*)carve(p, 11 * kGH * 4);
    _Float16* w2t  = (_Float16*)carve(p, (size_t)kGH * kGH * 2);
    float* pooled  = (float*)carve(p, (size_t)2 * kG * kGH * 4);
    float* gfc     = (float*)carve(p, (size_t)2 * kG * kGH * 4);
    float* etmp    = (float*)carve(p, (size_t)2 * kG * kEH * 4);
    float* ento    = (float*)carve(p, (size_t)2 * kG * kEH * 4);
    float* dh1     = (float*)carve(p, (size_t)kG * kHID * 4);
    float* dh2     = (float*)carve(p, (size_t)kG * kHID * 4);

    // --- Graph structure + conv1 (kernel boundaries = safe grid barriers) ---
    hipMemsetAsync(counts, 0, (size_t)2 * kN * 4, stream);
    prep_kernel<<<267, 256, 0, stream>>>(atom_emb, gW1, gW2, M11, w2t);
    rank_ell_kernel<<<dim3(kE / 256, 2), 256, 0, stream>>>(ei1, ei2, counts, col_ell);
    dinvx_kernel<<<dim3(kNB, 2), 256, 0, stream>>>(counts, dinv, xd, x1, x2);
    conv1_combine_kernel<<<dim3(kN / 16, 2), 256, 0, stream>>>(xd, counts, col_ell,
                                                               M11, gb1, h2_h);

    // --- Conv2 GEMM (MFMA f16, BN=128): hs8 = fp8(128 * dinv ⊙ (h2 @ W2)) ---
    gemm2_mfma_kernel<<<dim3((kN + 127) / 128, kGH / 128, 2), 256, 0, stream>>>(h2_h, w2t,
                                                                                dinv, hs8);
    // --- Conv2 aggregate -> h4 (reuses h2 buffer) ---
    aggregate2_kernel<<<dim3((kN + 3) / 4, 2), 256, 0, stream>>>(hs8, dinv, counts, col_ell,
                                                                 gb2, h2_h);
    // --- Mean-pool -> pooled [2G, GH], then fc via tiled GEMM -> gfc ---
    pool_kernel<<<dim3(kG, 2), 256, 0, stream>>>(h2_h, batch1, batch2, pooled);
    gemm32_kernel<<<dim3(kGH / 64, 2 * kG / 32), 256, 0, stream>>>(pooled, fcW, gfc,
                                                                   2 * kG, kGH, kGH, fcb, 0);

    // --- Entity encoders (gather+relu fused into eW1; eW2 on 32-row tiles) ---
    gemm_entgather_kernel<<<dim3(kEH / 64, 2 * kG / 64), 256, 0, stream>>>(ent_emb, ent1, ent2,
                                                                           eW1, etmp, kEH, eb1);
    gemm32_kernel<<<dim3(kEH / 64, 2 * kG / 32), 256, 0, stream>>>(etmp, eW2, ento,
                                                                   2 * kG, kEH, kEH, eb2, 1);
    // --- Decoder (egs fused into dW1; dW2/dW3 on 32-row tiles) ---
    gemm_egs_kernel<<<dim3(kHID / 64, kG / 64), 256, 0, stream>>>(gfc, ento, dW1, dh1,
                                                                  kHID, db1);
    gemm32_kernel<<<dim3(kHID / 64, kG / 32), 256, 0, stream>>>(dh1, dW2, dh2,
                                                                kG, kHID, kHID, db2, 1);
    gemm32_kernel<<<dim3(kOUT / 64, kG / 32), 256, 0, stream>>>(dh2, dW3, out,
                                                                kG, kOUT, kHID, db3, 0);
}

// Round 6
// 522.551 us; speedup vs baseline: 1.1417x; 1.1205x over previous
//
#include <hip/hip_runtime.h>
#include <hip/hip_fp16.h>

// Problem constants
static constexpr int kN = 50000;      // nodes per side
static constexpr int kE = 800000;     // edges per side
static constexpr int kG = 1024;       // graphs per batch
static constexpr int kEMB = 128;
static constexpr int kGH = 256;
static constexpr int kEH = 256;
static constexpr int kOUT = 128;
static constexpr int kHID = 512;
static constexpr int kNB = (kN + 255) / 256;   // 196 chunks per side
static constexpr int kMD = 64;        // ELL stride; deg ~ Poisson(16), P(deg>=64)~e^-125
static constexpr int kNBKT = 196;     // dst buckets of 256 nodes (50000 -> 196)
static constexpr int kEPB = 3125;     // edges per bin block; 256 blocks exactly
static constexpr int kPBLK = 256;     // bin blocks per side (256*3125 = 800000)

typedef __attribute__((ext_vector_type(8))) _Float16 half8v;
typedef __attribute__((ext_vector_type(4))) _Float16 half4v;
typedef __attribute__((ext_vector_type(4))) float floatx4;
typedef __attribute__((ext_vector_type(2))) float floatx2;

// NOTE (R6): cross-XCD plain-data handoff through grid.sync() gave stale reads.
// NOTE (R7/R12): device atomics memory-side; floor is OP-COUNT ~21/ns.
// NOTE (R8): returning atomic = rank. (R10) lookback scan regressed.
// (R11) role-merged grids regressed. (R2) fp8 hs: 659->616us, absmax unchanged.
// (R3) conv1 DPP 16-lane groups: 616->596us. (R4) ushort/poolfc split NEUTRAL.
// NOTE (R5): ELL fusion: rank_ell 117us — ELL store did NOT hide under atomic
// floor (op-bound: 1.6M atomics + 1.6M random stores share the pipe; VALU 0.6%,
// HBM 10%). Net -11us only from killing scatter/scans.
// This revision (R6b): ZERO global atomics. dst-bucket binning (bucket=dst>>8):
// binp1 LDS hist -> scanA/scanB offsets -> binp2 block-local LDS bucket-sort +
// COALESCED bucket-major edge write -> binp3 per-bucket LDS slot counters,
// col_ell stores confined to 32KB windows; true degrees written (no memset).

// fp8 fixed scale: |hs| <~ 0.2 typ; x128 keeps values in e4m3 normal range.
#define HS_SCALE 128.0f
#define HS_INV   (1.0f / 128.0f)

__device__ inline void acc_fp8x4(unsigned int w, float& a0, float& a1, float& a2, float& a3) {
    floatx2 lo = __builtin_amdgcn_cvt_pk_f32_fp8(w, false);
    floatx2 hi = __builtin_amdgcn_cvt_pk_f32_fp8(w, true);
    a0 += lo[0]; a1 += lo[1]; a2 += hi[0]; a3 += hi[1];
}

// 16-lane group sum via DPP row_ror rotations (1,2,4,8).
__device__ inline float grp16_reduce(float v) {
    int x;
    x = __builtin_amdgcn_update_dpp(0, __float_as_int(v), 0x121, 0xF, 0xF, true);
    v += __int_as_float(x);
    x = __builtin_amdgcn_update_dpp(0, __float_as_int(v), 0x122, 0xF, 0xF, true);
    v += __int_as_float(x);
    x = __builtin_amdgcn_update_dpp(0, __float_as_int(v), 0x124, 0xF, 0xF, true);
    v += __int_as_float(x);
    x = __builtin_amdgcn_update_dpp(0, __float_as_int(v), 0x128, 0xF, 0xF, true);
    v += __int_as_float(x);
    return v;
}

// ---------------------------------------------------------------------------
// prep: w2t = fp16(gW2^T) (blocks 0..255), M11 = atom_emb@gW1 (blocks 256..266)
// ---------------------------------------------------------------------------
__global__ void prep_kernel(const float* __restrict__ atom_emb, const float* __restrict__ gW1,
                            const float* __restrict__ gW2,
                            float* __restrict__ M11, _Float16* __restrict__ w2t) {
    int i = blockIdx.x * 256 + threadIdx.x;
    if (blockIdx.x < 256) {
        int k = i >> 8, n = i & 255;
        w2t[(size_t)n * kGH + k] = (_Float16)gW2[(size_t)k * kGH + n];
    } else {
        int j = i - 65536;
        if (j < 11 * kGH) {
            int r = j >> 8, c = j & 255;
            float s = 0.f;
            for (int k = 0; k < kEMB; k++) s += atom_emb[r * kEMB + k] * gW1[k * kGH + c];
            M11[j] = s;
        }
    }
}

// ---------------------------------------------------------------------------
// binp1: per-block LDS histogram over 196 dst-buckets.
// poff[(side*196+b)*256 + blk] = count of this block's edges in bucket b.
// ---------------------------------------------------------------------------
__global__ void binp1_kernel(const int* __restrict__ ei1, const int* __restrict__ ei2,
                             int* __restrict__ poff) {
    int side = blockIdx.y;
    const int* dst = (side ? ei2 : ei1) + kE;
    __shared__ int hist[kNBKT];
    int t = threadIdx.x;
    if (t < kNBKT) hist[t] = 0;
    __syncthreads();
    int base = blockIdx.x * kEPB;
    for (int j = t; j < kEPB; j += 256)
        atomicAdd(&hist[dst[base + j] >> 8], 1);
    __syncthreads();
    if (t < kNBKT) poff[((side * kNBKT + t) << 8) | blockIdx.x] = hist[t];
}

// scanA: per (side,bucket) exclusive scan over the 256 block counts (in place);
// bucket total -> btot.
__global__ void scanA_kernel(int* __restrict__ poff, int* __restrict__ btot) {
    int b = blockIdx.x, side = blockIdx.y, t = threadIdx.x;
    __shared__ int s[256];
    int idx = ((side * kNBKT + b) << 8) | t;
    int v = poff[idx];
    s[t] = v;
    __syncthreads();
    for (int o = 1; o < 256; o <<= 1) {
        int u = (t >= o) ? s[t - o] : 0;
        __syncthreads();
        s[t] += u;
        __syncthreads();
    }
    poff[idx] = s[t] - v;                    // exclusive within (side,bucket)
    if (t == 255) btot[side * kNBKT + b] = s[255];
}

// scanB: exclusive scan of bucket totals -> bbase[side][0..196] (197 entries).
__global__ void scanB_kernel(const int* __restrict__ btot, int* __restrict__ bbase) {
    int side = blockIdx.x, t = threadIdx.x;
    __shared__ int s[256];
    int v = (t < kNBKT) ? btot[side * kNBKT + t] : 0;
    s[t] = v;
    __syncthreads();
    for (int o = 1; o < 256; o <<= 1) {
        int u = (t >= o) ? s[t - o] : 0;
        __syncthreads();
        s[t] += u;
        __syncthreads();
    }
    if (t < kNBKT) bbase[side * (kNBKT + 1) + t] = s[t] - v;
    if (t == 255) bbase[side * (kNBKT + 1) + kNBKT] = s[255];
}

// ---------------------------------------------------------------------------
// binp2: block-local LDS bucket-sort of 3125 edges, then COALESCED bucket-major
// write-out of packed (dst<<16 | src). Runs of ~16 consecutive words per bucket
// replace 1.6M isolated random stores.
// ---------------------------------------------------------------------------
__launch_bounds__(256)
__global__ void binp2_kernel(const int* __restrict__ ei1, const int* __restrict__ ei2,
                             const int* __restrict__ poff, const int* __restrict__ bbase,
                             unsigned int* __restrict__ ebuf) {
    int side = blockIdx.y, blk = blockIdx.x, t = threadIdx.x;
    const int* ei = side ? ei2 : ei1;
    __shared__ int hist[kNBKT], lb[kNBKT], gb[kNBKT], scanbuf[256];
    __shared__ unsigned int sorted[kEPB];
    if (t < kNBKT) hist[t] = 0;
    __syncthreads();
    int base = blk * kEPB;
    for (int j = t; j < kEPB; j += 256)
        atomicAdd(&hist[ei[kE + base + j] >> 8], 1);
    __syncthreads();
    int v = (t < kNBKT) ? hist[t] : 0;
    scanbuf[t] = v;
    __syncthreads();
    for (int o = 1; o < 256; o <<= 1) {
        int u = (t >= o) ? scanbuf[t - o] : 0;
        __syncthreads();
        scanbuf[t] += u;
        __syncthreads();
    }
    if (t < kNBKT) {
        lb[t] = scanbuf[t] - v;              // local exclusive base
        gb[t] = bbase[side * (kNBKT + 1) + t] + poff[((side * kNBKT + t) << 8) | blk];
        hist[t] = 0;                         // reuse as running counter
    }
    __syncthreads();
    for (int j = t; j < kEPB; j += 256) {
        int s_ = ei[base + j];
        int d  = ei[kE + base + j];
        int b  = d >> 8;
        int r  = atomicAdd(&hist[b], 1);
        sorted[lb[b] + r] = ((unsigned int)d << 16) | (unsigned int)s_;
    }
    __syncthreads();
    for (int j = t; j < kEPB; j += 256) {
        unsigned int val = sorted[j];
        int b = val >> 24;                   // = dst >> 8
        int gpos = gb[b] + (j - lb[b]);
        ebuf[(size_t)side * kE + gpos] = val;
    }
}

// ---------------------------------------------------------------------------
// binp3: one block per bucket. LDS returning-atomic slot per node; col_ell
// stores confined to this bucket's 32KB window. Writes true degrees -> counts.
// ---------------------------------------------------------------------------
__global__ void binp3_kernel(const unsigned int* __restrict__ ebuf, const int* __restrict__ bbase,
                             unsigned short* __restrict__ col_ell, int* __restrict__ counts) {
    int b = blockIdx.x, side = blockIdx.y, t = threadIdx.x;
    __shared__ int cnt[256];
    cnt[t] = 0;
    __syncthreads();
    int start = bbase[side * (kNBKT + 1) + b];
    int end   = bbase[side * (kNBKT + 1) + b + 1];
    for (int k = start + t; k < end; k += 256) {
        unsigned int v = ebuf[(size_t)side * kE + k];
        int d8 = (v >> 16) & 255;
        int slot = atomicAdd(&cnt[d8], 1);
        if (slot > kMD - 1) slot = kMD - 1;  // unreachable; memory-safety only
        int node = (b << 8) | d8;
        col_ell[((size_t)side * kN + node) * kMD + slot] = (unsigned short)(v & 0xFFFFu);
    }
    __syncthreads();
    int node = (b << 8) | t;
    if (node < kN) counts[side * kN + node] = cnt[t];
}

// deg -> dinv = rsqrt(deg+1); xd[v] = (x[v], bits(dinv[v])).
__global__ void dinvx_kernel(const int* __restrict__ counts, float* __restrict__ dinv,
                             int2* __restrict__ xd,
                             const int* __restrict__ x1, const int* __restrict__ x2) {
    int side = blockIdx.y;
    int i = blockIdx.x * 256 + threadIdx.x;
    if (i >= kN) return;
    int v = counts[side * kN + i];
    float dv = rsqrtf((float)(v + 1));           // +1 self-loop
    dinv[side * kN + i] = dv;
    const int* x = side ? x2 : x1;
    xd[side * kN + i] = make_int2(x[i], __float_as_int(dv));
}

// ---------------------------------------------------------------------------
// Conv1 combine, 16-lane groups (4 nodes/wave), DPP reduce, zero LDS ops.
// ---------------------------------------------------------------------------
__global__ void conv1_combine_kernel(const int2* __restrict__ xd,
                                     const int* __restrict__ counts,
                                     const unsigned short* __restrict__ col_ell,
                                     const float* __restrict__ M11,
                                     const float* __restrict__ bias,
                                     _Float16* __restrict__ out) {
    int side = blockIdx.y;
    const int2* xdb = xd + (size_t)side * kN;
    const int* deg = counts + side * kN;
    const unsigned short* ci = col_ell + (size_t)side * kN * kMD;
    _Float16* ob = out + (size_t)side * kN * kGH;

    int tid = threadIdx.x;
    int sub = tid & 15;                 // lane within 16-lane group
    int v = blockIdx.x * 16 + (tid >> 4);   // node per group (exact: 3125*16=50000)

    int cnt = min(deg[v], kMD);
    const unsigned short* cv = ci + (size_t)v * kMD;
    float wt[11];
    #pragma unroll
    for (int t = 0; t < 11; t++) wt[t] = 0.f;
    for (int base = 0; base < cnt; base += 16) {
        int e = base + sub;
        int xs = 15; float ds = 0.f;
        if (e < cnt) {
            int2 t = xdb[(int)cv[e]];
            xs = t.x; ds = __int_as_float(t.y);
        }
        #pragma unroll
        for (int t = 0; t < 11; t++) wt[t] += (xs == t) ? ds : 0.f;
    }
    #pragma unroll
    for (int t = 0; t < 11; t++) wt[t] = grp16_reduce(wt[t]);

    int2 xv = xdb[v];
    float dv = __int_as_float(xv.y);
    #pragma unroll
    for (int q = 0; q < 4; q++) {
        int c = q * 64 + sub * 4;       // coalesced per group: 16 lanes x 16B
        float4 bia = *(const float4*)(bias + c);
        float4 m = *(const float4*)(M11 + xv.x * kGH + c);
        float4 acc = make_float4(dv * m.x, dv * m.y, dv * m.z, dv * m.w);
        #pragma unroll
        for (int t = 0; t < 11; t++) {
            float w = wt[t];
            float4 mt = *(const float4*)(M11 + t * kGH + c);
            acc.x += w * mt.x; acc.y += w * mt.y;
            acc.z += w * mt.z; acc.w += w * mt.w;
        }
        half4v o;
        o[0] = (_Float16)fmaxf(dv * acc.x + bia.x, 0.f);
        o[1] = (_Float16)fmaxf(dv * acc.y + bia.y, 0.f);
        o[2] = (_Float16)fmaxf(dv * acc.z + bia.z, 0.f);
        o[3] = (_Float16)fmaxf(dv * acc.w + bia.w, 0.f);
        *(half4v*)(ob + (size_t)v * kGH + c) = o;
    }
}

// ---------------------------------------------------------------------------
// Conv2 GEMM via MFMA f16, LDS-tiled: hs = fp8(HS_SCALE * dinv ⊙ (h2 @ W2))
// BM=128, BN=128, BK=64 (R9-measured config). 4 waves (2x2); wave = 64x64.
// ---------------------------------------------------------------------------
__launch_bounds__(256)
__global__ void gemm2_mfma_kernel(const _Float16* __restrict__ A,
                                  const _Float16* __restrict__ Bt,
                                  const float* __restrict__ dinv,
                                  unsigned char* __restrict__ C) {
    __shared__ _Float16 As[128][72];
    __shared__ _Float16 Bs[128][72];

    int side = blockIdx.z;
    const _Float16* Ab = A + (size_t)side * kN * kGH;
    const float* db = dinv + (size_t)side * kN;
    unsigned char* Cb = C + (size_t)side * kN * kGH;

    int tid = threadIdx.x;
    int wave = tid >> 6, lane = tid & 63;
    int quad = lane >> 4, r = lane & 15;
    int wm = wave >> 1, wn = wave & 1;
    int row0 = blockIdx.x * 128;
    int col0 = blockIdx.y * 128;

    floatx4 acc[4][4];
    #pragma unroll
    for (int i = 0; i < 4; i++)
        #pragma unroll
        for (int j = 0; j < 4; j++) acc[i][j] = (floatx4){0.f, 0.f, 0.f, 0.f};

    for (int k0 = 0; k0 < kGH; k0 += 64) {
        #pragma unroll
        for (int u = 0; u < 4; u++) {
            int idx = tid + u * 256;           // 0..1023
            int row = idx >> 3;                // 0..127
            int seg = (idx & 7) * 8;           // 0..56
            int gr = row0 + row;
            if (gr >= kN) gr = kN - 1;
            *(half8v*)&As[row][seg] = *(const half8v*)(Ab + (size_t)gr * kGH + k0 + seg);
            *(half8v*)&Bs[row][seg] = *(const half8v*)(Bt + (size_t)(col0 + row) * kGH + k0 + seg);
        }
        __syncthreads();
        #pragma unroll
        for (int ks = 0; ks < 2; ks++) {
            half8v af[4], bf[4];
            #pragma unroll
            for (int mt = 0; mt < 4; mt++)
                af[mt] = *(const half8v*)&As[wm * 64 + mt * 16 + r][ks * 32 + quad * 8];
            #pragma unroll
            for (int nt = 0; nt < 4; nt++)
                bf[nt] = *(const half8v*)&Bs[wn * 64 + nt * 16 + r][ks * 32 + quad * 8];
            #pragma unroll
            for (int mt = 0; mt < 4; mt++)
                #pragma unroll
                for (int nt = 0; nt < 4; nt++)
                    acc[mt][nt] = __builtin_amdgcn_mfma_f32_16x16x32_f16(af[mt], bf[nt],
                                                                         acc[mt][nt], 0, 0, 0);
        }
        __syncthreads();
    }

    // Epilogue: C/D layout col = r, row = quad*4 + i.  fp8 e4m3 store, x128.
    #pragma unroll
    for (int mt = 0; mt < 4; mt++) {
        #pragma unroll
        for (int i = 0; i < 4; i++) {
            int grow = row0 + wm * 64 + mt * 16 + quad * 4 + i;
            if (grow >= kN) continue;
            float rsq = db[grow] * HS_SCALE;
            #pragma unroll
            for (int nt = 0; nt < 4; nt++) {
                int gcol = col0 + wn * 64 + nt * 16 + r;
                float q = acc[mt][nt][i] * rsq;
                Cb[(size_t)grow * kGH + gcol] =
                    (unsigned char)__builtin_amdgcn_cvt_pk_fp8_f32(q, q, 0, false);
            }
        }
    }
}

// ---------------------------------------------------------------------------
// Conv2 aggregate: h4[v] = relu(dinv[v]*(hs[v] + sum_s hs[s])/HS_SCALE + b2)
// ---------------------------------------------------------------------------
__global__ void aggregate2_kernel(const unsigned char* __restrict__ hs, const float* __restrict__ dinv,
                                  const int* __restrict__ counts,
                                  const unsigned short* __restrict__ col_ell,
                                  const float* __restrict__ bias, _Float16* __restrict__ out) {
    int side = blockIdx.y;
    const unsigned char* hb = hs + (size_t)side * kN * kGH;
    const float* dv_ = dinv + side * kN;
    const int* deg = counts + side * kN;
    const unsigned short* ci = col_ell + (size_t)side * kN * kMD;
    _Float16* ob = out + (size_t)side * kN * kGH;

    int wave = threadIdx.x >> 6;
    int lane = threadIdx.x & 63;
    int v = blockIdx.x * 4 + wave;
    if (v >= kN) return;
    int c = lane * 4;
    float4 bia = *(const float4*)(bias + c);
    float dv = dv_[v];
    float a0 = 0.f, a1 = 0.f, a2 = 0.f, a3 = 0.f;
    acc_fp8x4(*(const unsigned int*)(hb + (size_t)v * kGH + c), a0, a1, a2, a3);  // self-loop
    int cnt = min(deg[v], kMD);
    int idxl = (lane < cnt) ? (int)ci[(size_t)v * kMD + lane] : 0;
    int j = 0;
    for (; j + 16 <= cnt; j += 16) {
        unsigned int w[16];
        #pragma unroll
        for (int u = 0; u < 16; u++)
            w[u] = *(const unsigned int*)(hb + (size_t)__shfl(idxl, j + u) * kGH + c);
        #pragma unroll
        for (int u = 0; u < 16; u++) acc_fp8x4(w[u], a0, a1, a2, a3);
    }
    for (; j + 8 <= cnt; j += 8) {
        unsigned int w[8];
        #pragma unroll
        for (int u = 0; u < 8; u++)
            w[u] = *(const unsigned int*)(hb + (size_t)__shfl(idxl, j + u) * kGH + c);
        #pragma unroll
        for (int u = 0; u < 8; u++) acc_fp8x4(w[u], a0, a1, a2, a3);
    }
    for (; j < cnt; j++)
        acc_fp8x4(*(const unsigned int*)(hb + (size_t)__shfl(idxl, j) * kGH + c),
                  a0, a1, a2, a3);
    float f = dv * HS_INV;
    half4v o;
    o[0] = (_Float16)fmaxf(f * a0 + bia.x, 0.f);
    o[1] = (_Float16)fmaxf(f * a1 + bia.y, 0.f);
    o[2] = (_Float16)fmaxf(f * a2 + bia.z, 0.f);
    o[3] = (_Float16)fmaxf(f * a3 + bia.w, 0.f);
    __builtin_nontemporal_store(o, (half4v*)(ob + (size_t)v * kGH + c));
}

// ---------------------------------------------------------------------------
// Mean-pool only: pooled[g] = mean_{v in g}(h4[v])  (fc via gemm32)
// ---------------------------------------------------------------------------
__global__ void pool_kernel(const _Float16* __restrict__ h,
                            const int* __restrict__ batch1, const int* __restrict__ batch2,
                            float* __restrict__ pooled) {
    int side = blockIdx.y;
    const _Float16* hb = h + (size_t)side * kN * kGH;
    const int* batch = side ? batch2 : batch1;
    int g = blockIdx.x;
    int lo = 0, hi = kN;
    while (lo < hi) { int mid = (lo + hi) >> 1; if (batch[mid] < g) lo = mid + 1; else hi = mid; }
    int start = lo;
    lo = start; hi = kN;
    while (lo < hi) { int mid = (lo + hi) >> 1; if (batch[mid] < g + 1) lo = mid + 1; else hi = mid; }
    int end = lo;
    int c = threadIdx.x;  // 256
    float s = 0.f;
    for (int v = start; v < end; v++) s += (float)hb[(size_t)v * kGH + c];
    pooled[(size_t)(side * kG + g) * kGH + c] = s / fmaxf((float)(end - start), 1.0f);
}

// ---------------------------------------------------------------------------
// Generic tiled fp32 GEMM, BM=32 BN=64 (tail layers).
// ---------------------------------------------------------------------------
__launch_bounds__(256)
__global__ void gemm32_kernel(const float* __restrict__ A, const float* __restrict__ B,
                              float* __restrict__ C, int M, int N, int K,
                              const float* __restrict__ bias, int relu) {
    __shared__ float As[16][32];
    __shared__ float Bs[16][64];
    int tid = threadIdx.x;
    int tx = tid & 15, ty = tid >> 4;
    int row0 = blockIdx.y * 32, col0 = blockIdx.x * 64;
    float acc[2][4] = {};
    for (int k0 = 0; k0 < K; k0 += 16) {
        {   // A tile 32x16, transposed into LDS (float2 per thread)
            int r = tid >> 3, seg = (tid & 7) * 2;
            int gr = row0 + r;
            float2 v = make_float2(0.f, 0.f);
            if (gr < M) v = *(const float2*)(A + (size_t)gr * K + k0 + seg);
            As[seg + 0][r] = v.x; As[seg + 1][r] = v.y;
        }
        {   // B tile 16x64
            int kr = tid >> 4, c4 = (tid & 15) * 4;
            float4 v = *(const float4*)(B + (size_t)(k0 + kr) * N + col0 + c4);
            *(float4*)&Bs[kr][c4] = v;
        }
        __syncthreads();
        #pragma unroll
        for (int k = 0; k < 16; k++) {
            float a[2], b[4];
            #pragma unroll
            for (int i = 0; i < 2; i++) a[i] = As[k][ty * 2 + i];
            #pragma unroll
            for (int j = 0; j < 4; j++) b[j] = Bs[k][tx * 4 + j];
            #pragma unroll
            for (int i = 0; i < 2; i++)
                #pragma unroll
                for (int j = 0; j < 4; j++)
                    acc[i][j] += a[i] * b[j];
        }
        __syncthreads();
    }
    #pragma unroll
    for (int i = 0; i < 2; i++) {
        int gr = row0 + ty * 2 + i;
        if (gr >= M) continue;
        #pragma unroll
        for (int j = 0; j < 4; j++) {
            int gc = col0 + tx * 4 + j;
            float v = acc[i][j];
            if (bias) v += bias[gc];
            if (relu) v = fmaxf(v, 0.f);
            C[(size_t)gr * N + gc] = v;
        }
    }
}

// ---------------------------------------------------------------------------
// eW1 GEMM with fused entity gather+relu on the A-load.
// ---------------------------------------------------------------------------
__launch_bounds__(256)
__global__ void gemm_entgather_kernel(const float* __restrict__ emb,
                                      const int* __restrict__ ent1, const int* __restrict__ ent2,
                                      const float* __restrict__ B, float* __restrict__ C,
                                      int N, const float* __restrict__ bias) {
    __shared__ float As[16][64];
    __shared__ float Bs[16][64];
    int tid = threadIdx.x;
    int tx = tid & 15, ty = tid >> 4;
    int row0 = blockIdx.y * 64, col0 = blockIdx.x * 64;
    float acc[4][4] = {};
    for (int k0 = 0; k0 < kEMB; k0 += 16) {
        {
            int r = tid >> 2, seg = tid & 3;
            int gr = row0 + r;                 // < 2G always
            int idx = (gr < kG) ? ent1[gr] : ent2[gr - kG];
            float4 v = *(const float4*)(emb + (size_t)idx * kEMB + k0 + seg * 4);
            As[seg * 4 + 0][r] = fmaxf(v.x, 0.f); As[seg * 4 + 1][r] = fmaxf(v.y, 0.f);
            As[seg * 4 + 2][r] = fmaxf(v.z, 0.f); As[seg * 4 + 3][r] = fmaxf(v.w, 0.f);
        }
        {
            int kr = tid >> 4, c4 = (tid & 15) * 4;
            float4 v = *(const float4*)(B + (size_t)(k0 + kr) * N + col0 + c4);
            *(float4*)&Bs[kr][c4] = v;
        }
        __syncthreads();
        #pragma unroll
        for (int k = 0; k < 16; k++) {
            float a[4], b[4];
            #pragma unroll
            for (int i = 0; i < 4; i++) a[i] = As[k][ty * 4 + i];
            #pragma unroll
            for (int j = 0; j < 4; j++) b[j] = Bs[k][tx * 4 + j];
            #pragma unroll
            for (int i = 0; i < 4; i++)
                #pragma unroll
                for (int j = 0; j < 4; j++)
                    acc[i][j] += a[i] * b[j];
        }
        __syncthreads();
    }
    #pragma unroll
    for (int i = 0; i < 4; i++) {
        int gr = row0 + ty * 4 + i;
        #pragma unroll
        for (int j = 0; j < 4; j++) {
            int gc = col0 + tx * 4 + j;
            C[(size_t)gr * N + gc] = fmaxf(acc[i][j] + bias[gc], 0.f);
        }
    }
}

// ---------------------------------------------------------------------------
// dW1 GEMM with fused egs computation on the A-load.
// ---------------------------------------------------------------------------
__launch_bounds__(256)
__global__ void gemm_egs_kernel(const float* __restrict__ gfc, const float* __restrict__ ento,
                                const float* __restrict__ B, float* __restrict__ C,
                                int N, const float* __restrict__ bias) {
    __shared__ float As[16][64];
    __shared__ float Bs[16][64];
    int tid = threadIdx.x;
    int tx = tid & 15, ty = tid >> 4;
    int row0 = blockIdx.y * 64, col0 = blockIdx.x * 64;
    float acc[4][4] = {};
    for (int k0 = 0; k0 < kHID; k0 += 16) {
        {
            int r = tid >> 2, seg = tid & 3;
            int gr = row0 + r;                 // < G always
            int k = k0 + seg * 4;
            float4 va, vb;
            if (k < kGH) {
                va = *(const float4*)(gfc + (size_t)gr * kGH + k);
                vb = *(const float4*)(gfc + (size_t)(gr + kG) * kGH + k);
            } else {
                va = *(const float4*)(ento + (size_t)gr * kEH + k - kGH);
                vb = *(const float4*)(ento + (size_t)(gr + kG) * kEH + k - kGH);
            }
            As[seg * 4 + 0][r] = fmaxf(va.x + vb.x, 0.f);
            As[seg * 4 + 1][r] = fmaxf(va.y + vb.y, 0.f);
            As[seg * 4 + 2][r] = fmaxf(va.z + vb.z, 0.f);
            As[seg * 4 + 3][r] = fmaxf(va.w + vb.w, 0.f);
        }
        {
            int kr = tid >> 4, c4 = (tid & 15) * 4;
            float4 v = *(const float4*)(B + (size_t)(k0 + kr) * N + col0 + c4);
            *(float4*)&Bs[kr][c4] = v;
        }
        __syncthreads();
        #pragma unroll
        for (int k = 0; k < 16; k++) {
            float a[4], b[4];
            #pragma unroll
            for (int i = 0; i < 4; i++) a[i] = As[k][ty * 4 + i];
            #pragma unroll
            for (int j = 0; j < 4; j++) b[j] = Bs[k][tx * 4 + j];
            #pragma unroll
            for (int i = 0; i < 4; i++)
                #pragma unroll
                for (int j = 0; j < 4; j++)
                    acc[i][j] += a[i] * b[j];
        }
        __syncthreads();
    }
    #pragma unroll
    for (int i = 0; i < 4; i++) {
        int gr = row0 + ty * 4 + i;
        #pragma unroll
        for (int j = 0; j < 4; j++) {
            int gc = col0 + tx * 4 + j;
            C[(size_t)gr * N + gc] = fmaxf(acc[i][j] + bias[gc], 0.f);
        }
    }
}

// ---------------------------------------------------------------------------
// Host launch
// ---------------------------------------------------------------------------
static inline char* carve(char*& p, size_t bytes) {
    char* r = p;
    p += (bytes + 255) & ~(size_t)255;
    return r;
}

extern "C" void kernel_launch(void* const* d_in, const int* in_sizes, int n_in,
                              void* d_out, int out_size, void* d_ws, size_t ws_size,
                              hipStream_t stream) {
    const int*   x1       = (const int*)d_in[0];
    const int*   ei1      = (const int*)d_in[1];
    const int*   ent1     = (const int*)d_in[2];
    const int*   batch1   = (const int*)d_in[3];
    const int*   x2       = (const int*)d_in[4];
    const int*   ei2      = (const int*)d_in[5];
    const int*   ent2     = (const int*)d_in[6];
    const int*   batch2   = (const int*)d_in[7];
    const float* atom_emb = (const float*)d_in[8];
    const float* gW1      = (const float*)d_in[9];
    const float* gb1      = (const float*)d_in[10];
    const float* gW2      = (const float*)d_in[11];
    const float* gb2      = (const float*)d_in[12];
    const float* fcW      = (const float*)d_in[13];
    const float* fcb      = (const float*)d_in[14];
    const float* ent_emb  = (const float*)d_in[15];
    const float* eW1      = (const float*)d_in[16];
    const float* eb1      = (const float*)d_in[17];
    const float* eW2      = (const float*)d_in[18];
    const float* eb2      = (const float*)d_in[19];
    const float* dW1      = (const float*)d_in[20];
    const float* db1      = (const float*)d_in[21];
    const float* dW2      = (const float*)d_in[22];
    const float* db2      = (const float*)d_in[23];
    const float* dW3      = (const float*)d_in[24];
    const float* db3      = (const float*)d_in[25];
    float* out = (float*)d_out;

    // Workspace carve (no zeroed spans needed — binp3 writes all counts).
    char* p = (char*)d_ws;
    _Float16* h2_h   = (_Float16*)carve(p, (size_t)2 * kN * kGH * 2);  // also h4
    unsigned char* hs8 = (unsigned char*)carve(p, (size_t)2 * kN * kGH); // fp8 hs
    unsigned short* col_ell = (unsigned short*)carve(p, (size_t)2 * kN * kMD * 2);
    unsigned int* ebuf = (unsigned int*)carve(p, (size_t)2 * kE * 4);
    int*   poff    = (int*)  carve(p, (size_t)2 * kNBKT * 256 * 4);
    int*   btot    = (int*)  carve(p, (size_t)2 * kNBKT * 4);
    int*   bbase   = (int*)  carve(p, (size_t)2 * (kNBKT + 1) * 4);
    int*   counts  = (int*)  carve(p, (size_t)2 * kN * 4);
    float* dinv    = (float*)carve(p, (size_t)2 * kN * 4);
    int2*  xd      = (int2*) carve(p, (size_t)2 * kN * 8);
    float* M11     = (float*)carve(p, 11 * kGH * 4);
    _Float16* w2t  = (_Float16*)carve(p, (size_t)kGH * kGH * 2);
    float* pooled  = (float*)carve(p, (size_t)2 * kG * kGH * 4);
    float* gfc     = (float*)carve(p, (size_t)2 * kG * kGH * 4);
    float* etmp    = (float*)carve(p, (size_t)2 * kG * kEH * 4);
    float* ento    = (float*)carve(p, (size_t)2 * kG * kEH * 4);
    float* dh1     = (float*)carve(p, (size_t)kG * kHID * 4);
    float* dh2     = (float*)carve(p, (size_t)kG * kHID * 4);

    // --- Graph structure via LDS binning (zero global atomics) + conv1 ---
    prep_kernel<<<267, 256, 0, stream>>>(atom_emb, gW1, gW2, M11, w2t);
    binp1_kernel<<<dim3(kPBLK, 2), 256, 0, stream>>>(ei1, ei2, poff);
    scanA_kernel<<<dim3(kNBKT, 2), 256, 0, stream>>>(poff, btot);
    scanB_kernel<<<2, 256, 0, stream>>>(btot, bbase);
    binp2_kernel<<<dim3(kPBLK, 2), 256, 0, stream>>>(ei1, ei2, poff, bbase, ebuf);
    binp3_kernel<<<dim3(kNBKT, 2), 256, 0, stream>>>(ebuf, bbase, col_ell, counts);
    dinvx_kernel<<<dim3(kNB, 2), 256, 0, stream>>>(counts, dinv, xd, x1, x2);
    conv1_combine_kernel<<<dim3(kN / 16, 2), 256, 0, stream>>>(xd, counts, col_ell,
                                                               M11, gb1, h2_h);

    // --- Conv2 GEMM (MFMA f16, BN=128): hs8 = fp8(128 * dinv ⊙ (h2 @ W2)) ---
    gemm2_mfma_kernel<<<dim3((kN + 127) / 128, kGH / 128, 2), 256, 0, stream>>>(h2_h, w2t,
                                                                                dinv, hs8);
    // --- Conv2 aggregate -> h4 (reuses h2 buffer) ---
    aggregate2_kernel<<<dim3((kN + 3) / 4, 2), 256, 0, stream>>>(hs8, dinv, counts, col_ell,
                                                                 gb2, h2_h);
    // --- Mean-pool -> pooled [2G, GH], then fc via tiled GEMM -> gfc ---
    pool_kernel<<<dim3(kG, 2), 256, 0, stream>>>(h2_h, batch1, batch2, pooled);
    gemm32_kernel<<<dim3(kGH / 64, 2 * kG / 32), 256, 0, stream>>>(pooled, fcW, gfc,
                                                                   2 * kG, kGH, kGH, fcb, 0);

    // --- Entity encoders (gather+relu fused into eW1; eW2 on 32-row tiles) ---
    gemm_entgather_kernel<<<dim3(kEH / 64, 2 * kG / 64), 256, 0, stream>>>(ent_emb, ent1, ent2,
                                                                           eW1, etmp, kEH, eb1);
    gemm32_kernel<<<dim3(kEH / 64, 2 * kG / 32), 256, 0, stream>>>(etmp, eW2, ento,
                                                                   2 * kG, kEH, kEH, eb2, 1);
    // --- Decoder (egs fused into dW1; dW2/dW3 on 32-row tiles) ---
    gemm_egs_kernel<<<dim3(kHID / 64, kG / 64), 256, 0, stream>>>(gfc, ento, dW1, dh1,
                                                                  kHID, db1);
    gemm32_kernel<<<dim3(kHID / 64, kG / 32), 256, 0, stream>>>(dh1, dW2, dh2,
                                                                kG, kHID, kHID, db2, 1);
    gemm32_kernel<<<dim3(kOUT / 64, kG / 32), 256, 0, stream>>>(dh2, dW3, out,
                                                                kG, kOUT, kHID, db3, 0);
}

// Round 7
// 438.758 us; speedup vs baseline: 1.3598x; 1.1910x over previous
//
#include <hip/hip_runtime.h>
#include <hip/hip_fp16.h>

// Problem constants
static constexpr int kN = 50000;      // nodes per side
static constexpr int kE = 800000;     // edges per side
static constexpr int kG = 1024;       // graphs per batch
static constexpr int kEMB = 128;
static constexpr int kGH = 256;
static constexpr int kEH = 256;
static constexpr int kOUT = 128;
static constexpr int kHID = 512;
static constexpr int kNB = (kN + 255) / 256;   // 196 chunks per side
static constexpr int kMD = 64;        // ELL stride; deg ~ Poisson(16), P(deg>=64)~e^-125
static constexpr int kNBKT = 196;     // dst buckets of 256 nodes (50000 -> 196)
static constexpr int kEPB = 3125;     // edges per bin block; 256 blocks exactly
static constexpr int kPBLK = 256;     // bin blocks per side (256*3125 = 800000)

typedef __attribute__((ext_vector_type(8))) _Float16 half8v;
typedef __attribute__((ext_vector_type(4))) _Float16 half4v;
typedef __attribute__((ext_vector_type(4))) float floatx4;
typedef __attribute__((ext_vector_type(2))) float floatx2;

// NOTE (R6): cross-XCD plain-data handoff through grid.sync() gave stale reads.
// NOTE (R7/R12): device atomics memory-side; floor is OP-COUNT ~21/ns.
// (R10) lookback scan regressed. (R11) role-merged grids regressed.
// (R2) fp8 hs: 659->616us. (R3) conv1 DPP groups: ->596us. (R4) NEUTRAL.
// (R5) ELL fusion: rank_ell 117us (atomic+random-store share mem-op pipe).
// (R6) LDS bucket binning, zero global atomics: 585->523us. gemm_egs exposed
// at 67us with Occupancy 5.4%, VALU 8% — the fp32 tail GEMMs are launch-width/
// latency-bound (64-256 blocks for 256 CUs).
// This revision (R7): unified fp16-MFMA tail GEMM (64x64 tile, fp32 accum,
// same verified fragment layout as gemm2) for fc/eW1/eW2/dW1/dW2/dW3 +
// fp16 feeders (pool, egather, egsprep) + one weight-transpose pass.
// Deliberate risk: fp16 tail adds ~1e-3 rel error -> absmax may rise to ~1e-3.

// fp8 fixed scale: |hs| <~ 0.2 typ; x128 keeps values in e4m3 normal range.
#define HS_SCALE 128.0f
#define HS_INV   (1.0f / 128.0f)

__device__ inline void acc_fp8x4(unsigned int w, float& a0, float& a1, float& a2, float& a3) {
    floatx2 lo = __builtin_amdgcn_cvt_pk_f32_fp8(w, false);
    floatx2 hi = __builtin_amdgcn_cvt_pk_f32_fp8(w, true);
    a0 += lo[0]; a1 += lo[1]; a2 += hi[0]; a3 += hi[1];
}

// 16-lane group sum via DPP row_ror rotations (1,2,4,8).
__device__ inline float grp16_reduce(float v) {
    int x;
    x = __builtin_amdgcn_update_dpp(0, __float_as_int(v), 0x121, 0xF, 0xF, true);
    v += __int_as_float(x);
    x = __builtin_amdgcn_update_dpp(0, __float_as_int(v), 0x122, 0xF, 0xF, true);
    v += __int_as_float(x);
    x = __builtin_amdgcn_update_dpp(0, __float_as_int(v), 0x124, 0xF, 0xF, true);
    v += __int_as_float(x);
    x = __builtin_amdgcn_update_dpp(0, __float_as_int(v), 0x128, 0xF, 0xF, true);
    v += __int_as_float(x);
    return v;
}

// ---------------------------------------------------------------------------
// prep: w2t = fp16(gW2^T) (blocks 0..255), M11 = atom_emb@gW1 (blocks 256..266)
// ---------------------------------------------------------------------------
__global__ void prep_kernel(const float* __restrict__ atom_emb, const float* __restrict__ gW1,
                            const float* __restrict__ gW2,
                            float* __restrict__ M11, _Float16* __restrict__ w2t) {
    int i = blockIdx.x * 256 + threadIdx.x;
    if (blockIdx.x < 256) {
        int k = i >> 8, n = i & 255;
        w2t[(size_t)n * kGH + k] = (_Float16)gW2[(size_t)k * kGH + n];
    } else {
        int j = i - 65536;
        if (j < 11 * kGH) {
            int r = j >> 8, c = j & 255;
            float s = 0.f;
            for (int k = 0; k < kEMB; k++) s += atom_emb[r * kEMB + k] * gW1[k * kGH + c];
            M11[j] = s;
        }
    }
}

// ---------------------------------------------------------------------------
// wtrans: all tail weights -> fp16 transposed ([N][K] from [K][N]).
// Block ranges: dW1 0..1023, dW2 1024..2047, dW3 2048..2303, fcW 2304..2559,
// eW1 2560..2687, eW2 2688..2943.  (2944 blocks total)
// ---------------------------------------------------------------------------
__global__ void wtrans_kernel(const float* __restrict__ dW1, const float* __restrict__ dW2,
                              const float* __restrict__ dW3, const float* __restrict__ fcW,
                              const float* __restrict__ eW1, const float* __restrict__ eW2,
                              _Float16* __restrict__ dW1t, _Float16* __restrict__ dW2t,
                              _Float16* __restrict__ dW3t, _Float16* __restrict__ fcWt,
                              _Float16* __restrict__ eW1t, _Float16* __restrict__ eW2t) {
    int b = blockIdx.x;
    const float* src; _Float16* dst; int K, N, j0;
    if (b < 1024)      { src = dW1; dst = dW1t; K = 512; N = 512; j0 = b * 256; }
    else if (b < 2048) { src = dW2; dst = dW2t; K = 512; N = 512; j0 = (b - 1024) * 256; }
    else if (b < 2304) { src = dW3; dst = dW3t; K = 512; N = 128; j0 = (b - 2048) * 256; }
    else if (b < 2560) { src = fcW; dst = fcWt; K = 256; N = 256; j0 = (b - 2304) * 256; }
    else if (b < 2688) { src = eW1; dst = eW1t; K = 128; N = 256; j0 = (b - 2560) * 256; }
    else               { src = eW2; dst = eW2t; K = 256; N = 256; j0 = (b - 2688) * 256; }
    int j = j0 + threadIdx.x;            // dst linear: n*K + k
    int n = j / K, k = j - n * K;
    dst[j] = (_Float16)src[(size_t)k * N + n];
}

// ---------------------------------------------------------------------------
// binp1: per-block LDS histogram over 196 dst-buckets.
// ---------------------------------------------------------------------------
__global__ void binp1_kernel(const int* __restrict__ ei1, const int* __restrict__ ei2,
                             int* __restrict__ poff) {
    int side = blockIdx.y;
    const int* dst = (side ? ei2 : ei1) + kE;
    __shared__ int hist[kNBKT];
    int t = threadIdx.x;
    if (t < kNBKT) hist[t] = 0;
    __syncthreads();
    int base = blockIdx.x * kEPB;
    for (int j = t; j < kEPB; j += 256)
        atomicAdd(&hist[dst[base + j] >> 8], 1);
    __syncthreads();
    if (t < kNBKT) poff[((side * kNBKT + t) << 8) | blockIdx.x] = hist[t];
}

// scanA: per (side,bucket) exclusive scan over the 256 block counts.
__global__ void scanA_kernel(int* __restrict__ poff, int* __restrict__ btot) {
    int b = blockIdx.x, side = blockIdx.y, t = threadIdx.x;
    __shared__ int s[256];
    int idx = ((side * kNBKT + b) << 8) | t;
    int v = poff[idx];
    s[t] = v;
    __syncthreads();
    for (int o = 1; o < 256; o <<= 1) {
        int u = (t >= o) ? s[t - o] : 0;
        __syncthreads();
        s[t] += u;
        __syncthreads();
    }
    poff[idx] = s[t] - v;
    if (t == 255) btot[side * kNBKT + b] = s[255];
}

// scanB: exclusive scan of bucket totals -> bbase.
__global__ void scanB_kernel(const int* __restrict__ btot, int* __restrict__ bbase) {
    int side = blockIdx.x, t = threadIdx.x;
    __shared__ int s[256];
    int v = (t < kNBKT) ? btot[side * kNBKT + t] : 0;
    s[t] = v;
    __syncthreads();
    for (int o = 1; o < 256; o <<= 1) {
        int u = (t >= o) ? s[t - o] : 0;
        __syncthreads();
        s[t] += u;
        __syncthreads();
    }
    if (t < kNBKT) bbase[side * (kNBKT + 1) + t] = s[t] - v;
    if (t == 255) bbase[side * (kNBKT + 1) + kNBKT] = s[255];
}

// ---------------------------------------------------------------------------
// binp2: block-local LDS bucket-sort, coalesced bucket-major write-out.
// ---------------------------------------------------------------------------
__launch_bounds__(256)
__global__ void binp2_kernel(const int* __restrict__ ei1, const int* __restrict__ ei2,
                             const int* __restrict__ poff, const int* __restrict__ bbase,
                             unsigned int* __restrict__ ebuf) {
    int side = blockIdx.y, blk = blockIdx.x, t = threadIdx.x;
    const int* ei = side ? ei2 : ei1;
    __shared__ int hist[kNBKT], lb[kNBKT], gb[kNBKT], scanbuf[256];
    __shared__ unsigned int sorted[kEPB];
    if (t < kNBKT) hist[t] = 0;
    __syncthreads();
    int base = blk * kEPB;
    for (int j = t; j < kEPB; j += 256)
        atomicAdd(&hist[ei[kE + base + j] >> 8], 1);
    __syncthreads();
    int v = (t < kNBKT) ? hist[t] : 0;
    scanbuf[t] = v;
    __syncthreads();
    for (int o = 1; o < 256; o <<= 1) {
        int u = (t >= o) ? scanbuf[t - o] : 0;
        __syncthreads();
        scanbuf[t] += u;
        __syncthreads();
    }
    if (t < kNBKT) {
        lb[t] = scanbuf[t] - v;
        gb[t] = bbase[side * (kNBKT + 1) + t] + poff[((side * kNBKT + t) << 8) | blk];
        hist[t] = 0;
    }
    __syncthreads();
    for (int j = t; j < kEPB; j += 256) {
        int s_ = ei[base + j];
        int d  = ei[kE + base + j];
        int b  = d >> 8;
        int r  = atomicAdd(&hist[b], 1);
        sorted[lb[b] + r] = ((unsigned int)d << 16) | (unsigned int)s_;
    }
    __syncthreads();
    for (int j = t; j < kEPB; j += 256) {
        unsigned int val = sorted[j];
        int b = val >> 24;
        int gpos = gb[b] + (j - lb[b]);
        ebuf[(size_t)side * kE + gpos] = val;
    }
}

// ---------------------------------------------------------------------------
// binp3: one block per bucket; LDS slot counters; degrees -> counts.
// ---------------------------------------------------------------------------
__global__ void binp3_kernel(const unsigned int* __restrict__ ebuf, const int* __restrict__ bbase,
                             unsigned short* __restrict__ col_ell, int* __restrict__ counts) {
    int b = blockIdx.x, side = blockIdx.y, t = threadIdx.x;
    __shared__ int cnt[256];
    cnt[t] = 0;
    __syncthreads();
    int start = bbase[side * (kNBKT + 1) + b];
    int end   = bbase[side * (kNBKT + 1) + b + 1];
    for (int k = start + t; k < end; k += 256) {
        unsigned int v = ebuf[(size_t)side * kE + k];
        int d8 = (v >> 16) & 255;
        int slot = atomicAdd(&cnt[d8], 1);
        if (slot > kMD - 1) slot = kMD - 1;
        int node = (b << 8) | d8;
        col_ell[((size_t)side * kN + node) * kMD + slot] = (unsigned short)(v & 0xFFFFu);
    }
    __syncthreads();
    int node = (b << 8) | t;
    if (node < kN) counts[side * kN + node] = cnt[t];
}

// deg -> dinv = rsqrt(deg+1); xd[v] = (x[v], bits(dinv[v])).
__global__ void dinvx_kernel(const int* __restrict__ counts, float* __restrict__ dinv,
                             int2* __restrict__ xd,
                             const int* __restrict__ x1, const int* __restrict__ x2) {
    int side = blockIdx.y;
    int i = blockIdx.x * 256 + threadIdx.x;
    if (i >= kN) return;
    int v = counts[side * kN + i];
    float dv = rsqrtf((float)(v + 1));           // +1 self-loop
    dinv[side * kN + i] = dv;
    const int* x = side ? x2 : x1;
    xd[side * kN + i] = make_int2(x[i], __float_as_int(dv));
}

// ---------------------------------------------------------------------------
// Conv1 combine, 16-lane groups (4 nodes/wave), DPP reduce, zero LDS ops.
// ---------------------------------------------------------------------------
__global__ void conv1_combine_kernel(const int2* __restrict__ xd,
                                     const int* __restrict__ counts,
                                     const unsigned short* __restrict__ col_ell,
                                     const float* __restrict__ M11,
                                     const float* __restrict__ bias,
                                     _Float16* __restrict__ out) {
    int side = blockIdx.y;
    const int2* xdb = xd + (size_t)side * kN;
    const int* deg = counts + side * kN;
    const unsigned short* ci = col_ell + (size_t)side * kN * kMD;
    _Float16* ob = out + (size_t)side * kN * kGH;

    int tid = threadIdx.x;
    int sub = tid & 15;
    int v = blockIdx.x * 16 + (tid >> 4);

    int cnt = min(deg[v], kMD);
    const unsigned short* cv = ci + (size_t)v * kMD;
    float wt[11];
    #pragma unroll
    for (int t = 0; t < 11; t++) wt[t] = 0.f;
    for (int base = 0; base < cnt; base += 16) {
        int e = base + sub;
        int xs = 15; float ds = 0.f;
        if (e < cnt) {
            int2 t = xdb[(int)cv[e]];
            xs = t.x; ds = __int_as_float(t.y);
        }
        #pragma unroll
        for (int t = 0; t < 11; t++) wt[t] += (xs == t) ? ds : 0.f;
    }
    #pragma unroll
    for (int t = 0; t < 11; t++) wt[t] = grp16_reduce(wt[t]);

    int2 xv = xdb[v];
    float dv = __int_as_float(xv.y);
    #pragma unroll
    for (int q = 0; q < 4; q++) {
        int c = q * 64 + sub * 4;
        float4 bia = *(const float4*)(bias + c);
        float4 m = *(const float4*)(M11 + xv.x * kGH + c);
        float4 acc = make_float4(dv * m.x, dv * m.y, dv * m.z, dv * m.w);
        #pragma unroll
        for (int t = 0; t < 11; t++) {
            float w = wt[t];
            float4 mt = *(const float4*)(M11 + t * kGH + c);
            acc.x += w * mt.x; acc.y += w * mt.y;
            acc.z += w * mt.z; acc.w += w * mt.w;
        }
        half4v o;
        o[0] = (_Float16)fmaxf(dv * acc.x + bia.x, 0.f);
        o[1] = (_Float16)fmaxf(dv * acc.y + bia.y, 0.f);
        o[2] = (_Float16)fmaxf(dv * acc.z + bia.z, 0.f);
        o[3] = (_Float16)fmaxf(dv * acc.w + bia.w, 0.f);
        *(half4v*)(ob + (size_t)v * kGH + c) = o;
    }
}

// ---------------------------------------------------------------------------
// Conv2 GEMM via MFMA f16, LDS-tiled: hs = fp8(HS_SCALE * dinv ⊙ (h2 @ W2))
// BM=128, BN=128, BK=64. 4 waves (2x2); wave = 64x64.
// ---------------------------------------------------------------------------
__launch_bounds__(256)
__global__ void gemm2_mfma_kernel(const _Float16* __restrict__ A,
                                  const _Float16* __restrict__ Bt,
                                  const float* __restrict__ dinv,
                                  unsigned char* __restrict__ C) {
    __shared__ _Float16 As[128][72];
    __shared__ _Float16 Bs[128][72];

    int side = blockIdx.z;
    const _Float16* Ab = A + (size_t)side * kN * kGH;
    const float* db = dinv + (size_t)side * kN;
    unsigned char* Cb = C + (size_t)side * kN * kGH;

    int tid = threadIdx.x;
    int wave = tid >> 6, lane = tid & 63;
    int quad = lane >> 4, r = lane & 15;
    int wm = wave >> 1, wn = wave & 1;
    int row0 = blockIdx.x * 128;
    int col0 = blockIdx.y * 128;

    floatx4 acc[4][4];
    #pragma unroll
    for (int i = 0; i < 4; i++)
        #pragma unroll
        for (int j = 0; j < 4; j++) acc[i][j] = (floatx4){0.f, 0.f, 0.f, 0.f};

    for (int k0 = 0; k0 < kGH; k0 += 64) {
        #pragma unroll
        for (int u = 0; u < 4; u++) {
            int idx = tid + u * 256;
            int row = idx >> 3;
            int seg = (idx & 7) * 8;
            int gr = row0 + row;
            if (gr >= kN) gr = kN - 1;
            *(half8v*)&As[row][seg] = *(const half8v*)(Ab + (size_t)gr * kGH + k0 + seg);
            *(half8v*)&Bs[row][seg] = *(const half8v*)(Bt + (size_t)(col0 + row) * kGH + k0 + seg);
        }
        __syncthreads();
        #pragma unroll
        for (int ks = 0; ks < 2; ks++) {
            half8v af[4], bf[4];
            #pragma unroll
            for (int mt = 0; mt < 4; mt++)
                af[mt] = *(const half8v*)&As[wm * 64 + mt * 16 + r][ks * 32 + quad * 8];
            #pragma unroll
            for (int nt = 0; nt < 4; nt++)
                bf[nt] = *(const half8v*)&Bs[wn * 64 + nt * 16 + r][ks * 32 + quad * 8];
            #pragma unroll
            for (int mt = 0; mt < 4; mt++)
                #pragma unroll
                for (int nt = 0; nt < 4; nt++)
                    acc[mt][nt] = __builtin_amdgcn_mfma_f32_16x16x32_f16(af[mt], bf[nt],
                                                                         acc[mt][nt], 0, 0, 0);
        }
        __syncthreads();
    }

    #pragma unroll
    for (int mt = 0; mt < 4; mt++) {
        #pragma unroll
        for (int i = 0; i < 4; i++) {
            int grow = row0 + wm * 64 + mt * 16 + quad * 4 + i;
            if (grow >= kN) continue;
            float rsq = db[grow] * HS_SCALE;
            #pragma unroll
            for (int nt = 0; nt < 4; nt++) {
                int gcol = col0 + wn * 64 + nt * 16 + r;
                float q = acc[mt][nt][i] * rsq;
                Cb[(size_t)grow * kGH + gcol] =
                    (unsigned char)__builtin_amdgcn_cvt_pk_fp8_f32(q, q, 0, false);
            }
        }
    }
}

// ---------------------------------------------------------------------------
// Unified tail GEMM via MFMA f16 (fp32 accum): C = [relu](A @ B + bias)
// A [M,K] f16 row-major, Bt [N,K] f16. BM=BN=BK=64; 4 waves 2x2; wave=32x32.
// M,N,K all multiples of 64. f32out for the final layer.
// ---------------------------------------------------------------------------
__launch_bounds__(256)
__global__ void gemm_tail_kernel(const _Float16* __restrict__ A,
                                 const _Float16* __restrict__ Bt,
                                 void* __restrict__ Cout,
                                 int N, int K,
                                 const float* __restrict__ bias,
                                 int relu, int f32out) {
    __shared__ _Float16 As[64][72];
    __shared__ _Float16 Bs[64][72];
    int tid = threadIdx.x;
    int wave = tid >> 6, lane = tid & 63;
    int quad = lane >> 4, r = lane & 15;
    int wm = wave >> 1, wn = wave & 1;
    int row0 = blockIdx.x * 64, col0 = blockIdx.y * 64;

    floatx4 acc[2][2];
    #pragma unroll
    for (int i = 0; i < 2; i++)
        #pragma unroll
        for (int j = 0; j < 2; j++) acc[i][j] = (floatx4){0.f, 0.f, 0.f, 0.f};

    for (int k0 = 0; k0 < K; k0 += 64) {
        #pragma unroll
        for (int u = 0; u < 2; u++) {
            int idx = tid + u * 256;           // 0..511
            int row = idx >> 3;                // 0..63
            int seg = (idx & 7) * 8;           // 0..56
            *(half8v*)&As[row][seg] = *(const half8v*)(A + (size_t)(row0 + row) * K + k0 + seg);
            *(half8v*)&Bs[row][seg] = *(const half8v*)(Bt + (size_t)(col0 + row) * K + k0 + seg);
        }
        __syncthreads();
        #pragma unroll
        for (int ks = 0; ks < 2; ks++) {
            half8v af[2], bf[2];
            #pragma unroll
            for (int mt = 0; mt < 2; mt++)
                af[mt] = *(const half8v*)&As[wm * 32 + mt * 16 + r][ks * 32 + quad * 8];
            #pragma unroll
            for (int nt = 0; nt < 2; nt++)
                bf[nt] = *(const half8v*)&Bs[wn * 32 + nt * 16 + r][ks * 32 + quad * 8];
            #pragma unroll
            for (int mt = 0; mt < 2; mt++)
                #pragma unroll
                for (int nt = 0; nt < 2; nt++)
                    acc[mt][nt] = __builtin_amdgcn_mfma_f32_16x16x32_f16(af[mt], bf[nt],
                                                                         acc[mt][nt], 0, 0, 0);
        }
        __syncthreads();
    }

    #pragma unroll
    for (int mt = 0; mt < 2; mt++) {
        #pragma unroll
        for (int i = 0; i < 4; i++) {
            int grow = row0 + wm * 32 + mt * 16 + quad * 4 + i;
            #pragma unroll
            for (int nt = 0; nt < 2; nt++) {
                int gcol = col0 + wn * 32 + nt * 16 + r;
                float v = acc[mt][nt][i] + bias[gcol];
                if (relu) v = fmaxf(v, 0.f);
                if (f32out) ((float*)Cout)[(size_t)grow * N + gcol] = v;
                else ((_Float16*)Cout)[(size_t)grow * N + gcol] = (_Float16)v;
            }
        }
    }
}

// ---------------------------------------------------------------------------
// Conv2 aggregate: h4[v] = relu(dinv[v]*(hs[v] + sum_s hs[s])/HS_SCALE + b2)
// ---------------------------------------------------------------------------
__global__ void aggregate2_kernel(const unsigned char* __restrict__ hs, const float* __restrict__ dinv,
                                  const int* __restrict__ counts,
                                  const unsigned short* __restrict__ col_ell,
                                  const float* __restrict__ bias, _Float16* __restrict__ out) {
    int side = blockIdx.y;
    const unsigned char* hb = hs + (size_t)side * kN * kGH;
    const float* dv_ = dinv + side * kN;
    const int* deg = counts + side * kN;
    const unsigned short* ci = col_ell + (size_t)side * kN * kMD;
    _Float16* ob = out + (size_t)side * kN * kGH;

    int wave = threadIdx.x >> 6;
    int lane = threadIdx.x & 63;
    int v = blockIdx.x * 4 + wave;
    if (v >= kN) return;
    int c = lane * 4;
    float4 bia = *(const float4*)(bias + c);
    float dv = dv_[v];
    float a0 = 0.f, a1 = 0.f, a2 = 0.f, a3 = 0.f;
    acc_fp8x4(*(const unsigned int*)(hb + (size_t)v * kGH + c), a0, a1, a2, a3);  // self-loop
    int cnt = min(deg[v], kMD);
    int idxl = (lane < cnt) ? (int)ci[(size_t)v * kMD + lane] : 0;
    int j = 0;
    for (; j + 16 <= cnt; j += 16) {
        unsigned int w[16];
        #pragma unroll
        for (int u = 0; u < 16; u++)
            w[u] = *(const unsigned int*)(hb + (size_t)__shfl(idxl, j + u) * kGH + c);
        #pragma unroll
        for (int u = 0; u < 16; u++) acc_fp8x4(w[u], a0, a1, a2, a3);
    }
    for (; j + 8 <= cnt; j += 8) {
        unsigned int w[8];
        #pragma unroll
        for (int u = 0; u < 8; u++)
            w[u] = *(const unsigned int*)(hb + (size_t)__shfl(idxl, j + u) * kGH + c);
        #pragma unroll
        for (int u = 0; u < 8; u++) acc_fp8x4(w[u], a0, a1, a2, a3);
    }
    for (; j < cnt; j++)
        acc_fp8x4(*(const unsigned int*)(hb + (size_t)__shfl(idxl, j) * kGH + c),
                  a0, a1, a2, a3);
    float f = dv * HS_INV;
    half4v o;
    o[0] = (_Float16)fmaxf(f * a0 + bia.x, 0.f);
    o[1] = (_Float16)fmaxf(f * a1 + bia.y, 0.f);
    o[2] = (_Float16)fmaxf(f * a2 + bia.z, 0.f);
    o[3] = (_Float16)fmaxf(f * a3 + bia.w, 0.f);
    __builtin_nontemporal_store(o, (half4v*)(ob + (size_t)v * kGH + c));
}

// ---------------------------------------------------------------------------
// Mean-pool -> fp16: pooled16[side*G+g][c] = mean_{v in g}(h4[v][c])
// ---------------------------------------------------------------------------
__global__ void pool_kernel(const _Float16* __restrict__ h,
                            const int* __restrict__ batch1, const int* __restrict__ batch2,
                            _Float16* __restrict__ pooled16) {
    int side = blockIdx.y;
    const _Float16* hb = h + (size_t)side * kN * kGH;
    const int* batch = side ? batch2 : batch1;
    int g = blockIdx.x;
    int lo = 0, hi = kN;
    while (lo < hi) { int mid = (lo + hi) >> 1; if (batch[mid] < g) lo = mid + 1; else hi = mid; }
    int start = lo;
    lo = start; hi = kN;
    while (lo < hi) { int mid = (lo + hi) >> 1; if (batch[mid] < g + 1) lo = mid + 1; else hi = mid; }
    int end = lo;
    int c = threadIdx.x;  // 256
    float s = 0.f;
    for (int v = start; v < end; v++) s += (float)hb[(size_t)v * kGH + c];
    pooled16[(size_t)(side * kG + g) * kGH + c] = (_Float16)(s / fmaxf((float)(end - start), 1.0f));
}

// entity gather: e16[r][k] = fp16(relu(emb[ent[r]][k])), r in [0,2G)
__global__ void egather_kernel(const float* __restrict__ emb,
                               const int* __restrict__ ent1, const int* __restrict__ ent2,
                               _Float16* __restrict__ e16) {
    int rr = blockIdx.x;
    int idx = (rr < kG) ? ent1[rr] : ent2[rr - kG];
    int k = threadIdx.x;   // 128
    e16[(size_t)rr * kEMB + k] = (_Float16)fmaxf(emb[(size_t)idx * kEMB + k], 0.f);
}

// egs prep: egs16[g][k] = fp16(relu(eg1[g][k] + eg2[g][k]))
// eg rows: cols 0..255 from gfc16, 256..511 from ento16 (each [2G][256]).
__global__ void egsprep_kernel(const _Float16* __restrict__ gfc16,
                               const _Float16* __restrict__ ento16,
                               _Float16* __restrict__ egs16) {
    int idx = blockIdx.x * 256 + threadIdx.x;   // 0..65535
    int g = idx >> 6;                            // 0..1023
    int k8 = (idx & 63) * 8;                     // 0..504
    const _Float16* src = (k8 < kGH) ? gfc16 : ento16;
    int kk = (k8 < kGH) ? k8 : k8 - kGH;
    half8v a = *(const half8v*)(src + (size_t)g * kGH + kk);
    half8v b = *(const half8v*)(src + (size_t)(g + kG) * kGH + kk);
    half8v o;
    #pragma unroll
    for (int u = 0; u < 8; u++) o[u] = (_Float16)fmaxf((float)a[u] + (float)b[u], 0.f);
    *(half8v*)(egs16 + (size_t)g * kHID + k8) = o;
}

// ---------------------------------------------------------------------------
// Host launch
// ---------------------------------------------------------------------------
static inline char* carve(char*& p, size_t bytes) {
    char* r = p;
    p += (bytes + 255) & ~(size_t)255;
    return r;
}

extern "C" void kernel_launch(void* const* d_in, const int* in_sizes, int n_in,
                              void* d_out, int out_size, void* d_ws, size_t ws_size,
                              hipStream_t stream) {
    const int*   x1       = (const int*)d_in[0];
    const int*   ei1      = (const int*)d_in[1];
    const int*   ent1     = (const int*)d_in[2];
    const int*   batch1   = (const int*)d_in[3];
    const int*   x2       = (const int*)d_in[4];
    const int*   ei2      = (const int*)d_in[5];
    const int*   ent2     = (const int*)d_in[6];
    const int*   batch2   = (const int*)d_in[7];
    const float* atom_emb = (const float*)d_in[8];
    const float* gW1      = (const float*)d_in[9];
    const float* gb1      = (const float*)d_in[10];
    const float* gW2      = (const float*)d_in[11];
    const float* gb2      = (const float*)d_in[12];
    const float* fcW      = (const float*)d_in[13];
    const float* fcb      = (const float*)d_in[14];
    const float* ent_emb  = (const float*)d_in[15];
    const float* eW1      = (const float*)d_in[16];
    const float* eb1      = (const float*)d_in[17];
    const float* eW2      = (const float*)d_in[18];
    const float* eb2      = (const float*)d_in[19];
    const float* dW1      = (const float*)d_in[20];
    const float* db1      = (const float*)d_in[21];
    const float* dW2      = (const float*)d_in[22];
    const float* db2      = (const float*)d_in[23];
    const float* dW3      = (const float*)d_in[24];
    const float* db3      = (const float*)d_in[25];
    float* out = (float*)d_out;

    // Workspace carve (no zeroed spans needed — binp3 writes all counts).
    char* p = (char*)d_ws;
    _Float16* h2_h   = (_Float16*)carve(p, (size_t)2 * kN * kGH * 2);  // also h4
    unsigned char* hs8 = (unsigned char*)carve(p, (size_t)2 * kN * kGH); // fp8 hs
    unsigned short* col_ell = (unsigned short*)carve(p, (size_t)2 * kN * kMD * 2);
    unsigned int* ebuf = (unsigned int*)carve(p, (size_t)2 * kE * 4);
    int*   poff    = (int*)  carve(p, (size_t)2 * kNBKT * 256 * 4);
    int*   btot    = (int*)  carve(p, (size_t)2 * kNBKT * 4);
    int*   bbase   = (int*)  carve(p, (size_t)2 * (kNBKT + 1) * 4);
    int*   counts  = (int*)  carve(p, (size_t)2 * kN * 4);
    float* dinv    = (float*)carve(p, (size_t)2 * kN * 4);
    int2*  xd      = (int2*) carve(p, (size_t)2 * kN * 8);
    float* M11     = (float*)carve(p, 11 * kGH * 4);
    _Float16* w2t  = (_Float16*)carve(p, (size_t)kGH * kGH * 2);
    // fp16 tail buffers
    _Float16* pooled16 = (_Float16*)carve(p, (size_t)2 * kG * kGH * 2);
    _Float16* gfc16    = (_Float16*)carve(p, (size_t)2 * kG * kGH * 2);
    _Float16* e16      = (_Float16*)carve(p, (size_t)2 * kG * kEMB * 2);
    _Float16* etmp16   = (_Float16*)carve(p, (size_t)2 * kG * kEH * 2);
    _Float16* ento16   = (_Float16*)carve(p, (size_t)2 * kG * kEH * 2);
    _Float16* egs16    = (_Float16*)carve(p, (size_t)kG * kHID * 2);
    _Float16* dh1_16   = (_Float16*)carve(p, (size_t)kG * kHID * 2);
    _Float16* dh2_16   = (_Float16*)carve(p, (size_t)kG * kHID * 2);
    // fp16 transposed tail weights
    _Float16* dW1t = (_Float16*)carve(p, (size_t)kHID * kHID * 2);
    _Float16* dW2t = (_Float16*)carve(p, (size_t)kHID * kHID * 2);
    _Float16* dW3t = (_Float16*)carve(p, (size_t)kOUT * kHID * 2);
    _Float16* fcWt = (_Float16*)carve(p, (size_t)kGH * kGH * 2);
    _Float16* eW1t = (_Float16*)carve(p, (size_t)kEH * kEMB * 2);
    _Float16* eW2t = (_Float16*)carve(p, (size_t)kEH * kEH * 2);

    // --- Graph structure via LDS binning (zero global atomics) + conv1 ---
    prep_kernel<<<267, 256, 0, stream>>>(atom_emb, gW1, gW2, M11, w2t);
    wtrans_kernel<<<2944, 256, 0, stream>>>(dW1, dW2, dW3, fcW, eW1, eW2,
                                            dW1t, dW2t, dW3t, fcWt, eW1t, eW2t);
    binp1_kernel<<<dim3(kPBLK, 2), 256, 0, stream>>>(ei1, ei2, poff);
    scanA_kernel<<<dim3(kNBKT, 2), 256, 0, stream>>>(poff, btot);
    scanB_kernel<<<2, 256, 0, stream>>>(btot, bbase);
    binp2_kernel<<<dim3(kPBLK, 2), 256, 0, stream>>>(ei1, ei2, poff, bbase, ebuf);
    binp3_kernel<<<dim3(kNBKT, 2), 256, 0, stream>>>(ebuf, bbase, col_ell, counts);
    dinvx_kernel<<<dim3(kNB, 2), 256, 0, stream>>>(counts, dinv, xd, x1, x2);
    conv1_combine_kernel<<<dim3(kN / 16, 2), 256, 0, stream>>>(xd, counts, col_ell,
                                                               M11, gb1, h2_h);

    // --- Conv2 GEMM (MFMA f16): hs8 = fp8(128 * dinv ⊙ (h2 @ W2)) ---
    gemm2_mfma_kernel<<<dim3((kN + 127) / 128, kGH / 128, 2), 256, 0, stream>>>(h2_h, w2t,
                                                                                dinv, hs8);
    // --- Conv2 aggregate -> h4 (reuses h2 buffer) ---
    aggregate2_kernel<<<dim3((kN + 3) / 4, 2), 256, 0, stream>>>(hs8, dinv, counts, col_ell,
                                                                 gb2, h2_h);
    // --- Mean-pool (fp16) + entity gather (fp16) ---
    pool_kernel<<<dim3(kG, 2), 256, 0, stream>>>(h2_h, batch1, batch2, pooled16);
    egather_kernel<<<2 * kG, 128, 0, stream>>>(ent_emb, ent1, ent2, e16);

    // --- Tail GEMMs, all fp16 MFMA (fp32 accum) ---
    // gfc = pooled @ fcW + fcb  (no relu)
    gemm_tail_kernel<<<dim3(2 * kG / 64, kGH / 64), 256, 0, stream>>>(
        pooled16, fcWt, gfc16, kGH, kGH, fcb, 0, 0);
    // etmp = relu(e @ eW1 + eb1)
    gemm_tail_kernel<<<dim3(2 * kG / 64, kEH / 64), 256, 0, stream>>>(
        e16, eW1t, etmp16, kEH, kEMB, eb1, 1, 0);
    // ento = relu(etmp @ eW2 + eb2)
    gemm_tail_kernel<<<dim3(2 * kG / 64, kEH / 64), 256, 0, stream>>>(
        etmp16, eW2t, ento16, kEH, kEH, eb2, 1, 0);
    // egs = relu(eg1 + eg2)
    egsprep_kernel<<<kG * kHID / 8 / 256, 256, 0, stream>>>(gfc16, ento16, egs16);
    // dh1 = relu(egs @ dW1 + db1)
    gemm_tail_kernel<<<dim3(kG / 64, kHID / 64), 256, 0, stream>>>(
        egs16, dW1t, dh1_16, kHID, kHID, db1, 1, 0);
    // dh2 = relu(dh1 @ dW2 + db2)
    gemm_tail_kernel<<<dim3(kG / 64, kHID / 64), 256, 0, stream>>>(
        dh1_16, dW2t, dh2_16, kHID, kHID, db2, 1, 0);
    // out = dh2 @ dW3 + db3  (fp32 store)
    gemm_tail_kernel<<<dim3(kG / 64, kOUT / 64), 256, 0, stream>>>(
        dh2_16, dW3t, out, kOUT, kHID, db3, 0, 1);
}

// Round 8
// 428.871 us; speedup vs baseline: 1.3911x; 1.0231x over previous
//
#include <hip/hip_runtime.h>
#include <hip/hip_fp16.h>

// Problem constants
static constexpr int kN = 50000;      // nodes per side
static constexpr int kE = 800000;     // edges per side
static constexpr int kG = 1024;       // graphs per batch
static constexpr int kEMB = 128;
static constexpr int kGH = 256;
static constexpr int kEH = 256;
static constexpr int kOUT = 128;
static constexpr int kHID = 512;
static constexpr int kNB = (kN + 255) / 256;   // 196 chunks per side
static constexpr int kMD = 64;        // ELL stride; deg ~ Poisson(16), P(deg>=64)~e^-125
static constexpr int kNBKT = 196;     // dst buckets of 256 nodes (50000 -> 196)
static constexpr int kEPB = 3125;     // edges per bin block; 256 blocks exactly
static constexpr int kPBLK = 256;     // bin blocks per side (256*3125 = 800000)

typedef __attribute__((ext_vector_type(8))) _Float16 half8v;
typedef __attribute__((ext_vector_type(4))) _Float16 half4v;
typedef __attribute__((ext_vector_type(4))) float floatx4;
typedef __attribute__((ext_vector_type(2))) float floatx2;

// NOTE (R6): cross-XCD plain-data handoff through grid.sync() gave stale reads.
// NOTE (R7/R12): device atomics memory-side; floor is OP-COUNT ~21/ns.
// (R10) lookback scan regressed. (R11) role-merged grids regressed.
// (R2) fp8 hs: 659->616us. (R3) conv1 DPP groups: ->596us. (R4) NEUTRAL.
// (R5) ELL fusion regressed rank to 117us (atomics+random stores share pipe).
// (R6) LDS bucket binning, zero global atomics: 585->523us.
// (R7) fp16-MFMA unified tail: 523->439us, absmax UNCHANGED (fp16 tail free).
// aggregate2 top at 60.5us: fp8 gather roofline (FETCH 163MB, HBM 45%), but
// 50MB h4 write + 51MB pool re-read are round-trip waste — h4's only consumer
// is pool. This revision (R8): fuse pool into aggregate (one block per
// graph+side, 4 waves, nodes contiguous since batch sorted; per-wave fp32
// partial + LDS 4-way reduce -> pooled16 directly; h4 never materialized).
// Also fold dinvx into binp3 (degree already in LDS there).

// fp8 fixed scale: |hs| <~ 0.2 typ; x128 keeps values in e4m3 normal range.
#define HS_SCALE 128.0f
#define HS_INV   (1.0f / 128.0f)

__device__ inline void acc_fp8x4(unsigned int w, float& a0, float& a1, float& a2, float& a3) {
    floatx2 lo = __builtin_amdgcn_cvt_pk_f32_fp8(w, false);
    floatx2 hi = __builtin_amdgcn_cvt_pk_f32_fp8(w, true);
    a0 += lo[0]; a1 += lo[1]; a2 += hi[0]; a3 += hi[1];
}

// 16-lane group sum via DPP row_ror rotations (1,2,4,8).
__device__ inline float grp16_reduce(float v) {
    int x;
    x = __builtin_amdgcn_update_dpp(0, __float_as_int(v), 0x121, 0xF, 0xF, true);
    v += __int_as_float(x);
    x = __builtin_amdgcn_update_dpp(0, __float_as_int(v), 0x122, 0xF, 0xF, true);
    v += __int_as_float(x);
    x = __builtin_amdgcn_update_dpp(0, __float_as_int(v), 0x124, 0xF, 0xF, true);
    v += __int_as_float(x);
    x = __builtin_amdgcn_update_dpp(0, __float_as_int(v), 0x128, 0xF, 0xF, true);
    v += __int_as_float(x);
    return v;
}

// ---------------------------------------------------------------------------
// prep: w2t = fp16(gW2^T) (blocks 0..255), M11 = atom_emb@gW1 (blocks 256..266)
// ---------------------------------------------------------------------------
__global__ void prep_kernel(const float* __restrict__ atom_emb, const float* __restrict__ gW1,
                            const float* __restrict__ gW2,
                            float* __restrict__ M11, _Float16* __restrict__ w2t) {
    int i = blockIdx.x * 256 + threadIdx.x;
    if (blockIdx.x < 256) {
        int k = i >> 8, n = i & 255;
        w2t[(size_t)n * kGH + k] = (_Float16)gW2[(size_t)k * kGH + n];
    } else {
        int j = i - 65536;
        if (j < 11 * kGH) {
            int r = j >> 8, c = j & 255;
            float s = 0.f;
            for (int k = 0; k < kEMB; k++) s += atom_emb[r * kEMB + k] * gW1[k * kGH + c];
            M11[j] = s;
        }
    }
}

// ---------------------------------------------------------------------------
// wtrans: all tail weights -> fp16 transposed ([N][K] from [K][N]).
// ---------------------------------------------------------------------------
__global__ void wtrans_kernel(const float* __restrict__ dW1, const float* __restrict__ dW2,
                              const float* __restrict__ dW3, const float* __restrict__ fcW,
                              const float* __restrict__ eW1, const float* __restrict__ eW2,
                              _Float16* __restrict__ dW1t, _Float16* __restrict__ dW2t,
                              _Float16* __restrict__ dW3t, _Float16* __restrict__ fcWt,
                              _Float16* __restrict__ eW1t, _Float16* __restrict__ eW2t) {
    int b = blockIdx.x;
    const float* src; _Float16* dst; int K, N, j0;
    if (b < 1024)      { src = dW1; dst = dW1t; K = 512; N = 512; j0 = b * 256; }
    else if (b < 2048) { src = dW2; dst = dW2t; K = 512; N = 512; j0 = (b - 1024) * 256; }
    else if (b < 2304) { src = dW3; dst = dW3t; K = 512; N = 128; j0 = (b - 2048) * 256; }
    else if (b < 2560) { src = fcW; dst = fcWt; K = 256; N = 256; j0 = (b - 2304) * 256; }
    else if (b < 2688) { src = eW1; dst = eW1t; K = 128; N = 256; j0 = (b - 2560) * 256; }
    else               { src = eW2; dst = eW2t; K = 256; N = 256; j0 = (b - 2688) * 256; }
    int j = j0 + threadIdx.x;            // dst linear: n*K + k
    int n = j / K, k = j - n * K;
    dst[j] = (_Float16)src[(size_t)k * N + n];
}

// ---------------------------------------------------------------------------
// binp1: per-block LDS histogram over 196 dst-buckets.
// ---------------------------------------------------------------------------
__global__ void binp1_kernel(const int* __restrict__ ei1, const int* __restrict__ ei2,
                             int* __restrict__ poff) {
    int side = blockIdx.y;
    const int* dst = (side ? ei2 : ei1) + kE;
    __shared__ int hist[kNBKT];
    int t = threadIdx.x;
    if (t < kNBKT) hist[t] = 0;
    __syncthreads();
    int base = blockIdx.x * kEPB;
    for (int j = t; j < kEPB; j += 256)
        atomicAdd(&hist[dst[base + j] >> 8], 1);
    __syncthreads();
    if (t < kNBKT) poff[((side * kNBKT + t) << 8) | blockIdx.x] = hist[t];
}

// scanA: per (side,bucket) exclusive scan over the 256 block counts.
__global__ void scanA_kernel(int* __restrict__ poff, int* __restrict__ btot) {
    int b = blockIdx.x, side = blockIdx.y, t = threadIdx.x;
    __shared__ int s[256];
    int idx = ((side * kNBKT + b) << 8) | t;
    int v = poff[idx];
    s[t] = v;
    __syncthreads();
    for (int o = 1; o < 256; o <<= 1) {
        int u = (t >= o) ? s[t - o] : 0;
        __syncthreads();
        s[t] += u;
        __syncthreads();
    }
    poff[idx] = s[t] - v;
    if (t == 255) btot[side * kNBKT + b] = s[255];
}

// scanB: exclusive scan of bucket totals -> bbase.
__global__ void scanB_kernel(const int* __restrict__ btot, int* __restrict__ bbase) {
    int side = blockIdx.x, t = threadIdx.x;
    __shared__ int s[256];
    int v = (t < kNBKT) ? btot[side * kNBKT + t] : 0;
    s[t] = v;
    __syncthreads();
    for (int o = 1; o < 256; o <<= 1) {
        int u = (t >= o) ? s[t - o] : 0;
        __syncthreads();
        s[t] += u;
        __syncthreads();
    }
    if (t < kNBKT) bbase[side * (kNBKT + 1) + t] = s[t] - v;
    if (t == 255) bbase[side * (kNBKT + 1) + kNBKT] = s[255];
}

// ---------------------------------------------------------------------------
// binp2: block-local LDS bucket-sort, coalesced bucket-major write-out.
// ---------------------------------------------------------------------------
__launch_bounds__(256)
__global__ void binp2_kernel(const int* __restrict__ ei1, const int* __restrict__ ei2,
                             const int* __restrict__ poff, const int* __restrict__ bbase,
                             unsigned int* __restrict__ ebuf) {
    int side = blockIdx.y, blk = blockIdx.x, t = threadIdx.x;
    const int* ei = side ? ei2 : ei1;
    __shared__ int hist[kNBKT], lb[kNBKT], gb[kNBKT], scanbuf[256];
    __shared__ unsigned int sorted[kEPB];
    if (t < kNBKT) hist[t] = 0;
    __syncthreads();
    int base = blk * kEPB;
    for (int j = t; j < kEPB; j += 256)
        atomicAdd(&hist[ei[kE + base + j] >> 8], 1);
    __syncthreads();
    int v = (t < kNBKT) ? hist[t] : 0;
    scanbuf[t] = v;
    __syncthreads();
    for (int o = 1; o < 256; o <<= 1) {
        int u = (t >= o) ? scanbuf[t - o] : 0;
        __syncthreads();
        scanbuf[t] += u;
        __syncthreads();
    }
    if (t < kNBKT) {
        lb[t] = scanbuf[t] - v;
        gb[t] = bbase[side * (kNBKT + 1) + t] + poff[((side * kNBKT + t) << 8) | blk];
        hist[t] = 0;
    }
    __syncthreads();
    for (int j = t; j < kEPB; j += 256) {
        int s_ = ei[base + j];
        int d  = ei[kE + base + j];
        int b  = d >> 8;
        int r  = atomicAdd(&hist[b], 1);
        sorted[lb[b] + r] = ((unsigned int)d << 16) | (unsigned int)s_;
    }
    __syncthreads();
    for (int j = t; j < kEPB; j += 256) {
        unsigned int val = sorted[j];
        int b = val >> 24;
        int gpos = gb[b] + (j - lb[b]);
        ebuf[(size_t)side * kE + gpos] = val;
    }
}

// ---------------------------------------------------------------------------
// binp3: one block per bucket; LDS slot counters; col_ell stores in a 32KB
// window. Fused epilogue (was dinvx): degrees->counts, dinv, xd.
// ---------------------------------------------------------------------------
__global__ void binp3_kernel(const unsigned int* __restrict__ ebuf, const int* __restrict__ bbase,
                             unsigned short* __restrict__ col_ell, int* __restrict__ counts,
                             float* __restrict__ dinv, int2* __restrict__ xd,
                             const int* __restrict__ x1, const int* __restrict__ x2) {
    int b = blockIdx.x, side = blockIdx.y, t = threadIdx.x;
    __shared__ int cnt[256];
    cnt[t] = 0;
    __syncthreads();
    int start = bbase[side * (kNBKT + 1) + b];
    int end   = bbase[side * (kNBKT + 1) + b + 1];
    for (int k = start + t; k < end; k += 256) {
        unsigned int v = ebuf[(size_t)side * kE + k];
        int d8 = (v >> 16) & 255;
        int slot = atomicAdd(&cnt[d8], 1);
        if (slot > kMD - 1) slot = kMD - 1;
        int node = (b << 8) | d8;
        col_ell[((size_t)side * kN + node) * kMD + slot] = (unsigned short)(v & 0xFFFFu);
    }
    __syncthreads();
    int node = (b << 8) | t;
    if (node < kN) {
        int d = cnt[t];
        counts[side * kN + node] = d;
        float dv = rsqrtf((float)(d + 1));           // +1 self-loop
        dinv[side * kN + node] = dv;
        const int* x = side ? x2 : x1;
        xd[side * kN + node] = make_int2(x[node], __float_as_int(dv));
    }
}

// ---------------------------------------------------------------------------
// Conv1 combine, 16-lane groups (4 nodes/wave), DPP reduce, zero LDS ops.
// ---------------------------------------------------------------------------
__global__ void conv1_combine_kernel(const int2* __restrict__ xd,
                                     const int* __restrict__ counts,
                                     const unsigned short* __restrict__ col_ell,
                                     const float* __restrict__ M11,
                                     const float* __restrict__ bias,
                                     _Float16* __restrict__ out) {
    int side = blockIdx.y;
    const int2* xdb = xd + (size_t)side * kN;
    const int* deg = counts + side * kN;
    const unsigned short* ci = col_ell + (size_t)side * kN * kMD;
    _Float16* ob = out + (size_t)side * kN * kGH;

    int tid = threadIdx.x;
    int sub = tid & 15;
    int v = blockIdx.x * 16 + (tid >> 4);

    int cnt = min(deg[v], kMD);
    const unsigned short* cv = ci + (size_t)v * kMD;
    float wt[11];
    #pragma unroll
    for (int t = 0; t < 11; t++) wt[t] = 0.f;
    for (int base = 0; base < cnt; base += 16) {
        int e = base + sub;
        int xs = 15; float ds = 0.f;
        if (e < cnt) {
            int2 t = xdb[(int)cv[e]];
            xs = t.x; ds = __int_as_float(t.y);
        }
        #pragma unroll
        for (int t = 0; t < 11; t++) wt[t] += (xs == t) ? ds : 0.f;
    }
    #pragma unroll
    for (int t = 0; t < 11; t++) wt[t] = grp16_reduce(wt[t]);

    int2 xv = xdb[v];
    float dv = __int_as_float(xv.y);
    #pragma unroll
    for (int q = 0; q < 4; q++) {
        int c = q * 64 + sub * 4;
        float4 bia = *(const float4*)(bias + c);
        float4 m = *(const float4*)(M11 + xv.x * kGH + c);
        float4 acc = make_float4(dv * m.x, dv * m.y, dv * m.z, dv * m.w);
        #pragma unroll
        for (int t = 0; t < 11; t++) {
            float w = wt[t];
            float4 mt = *(const float4*)(M11 + t * kGH + c);
            acc.x += w * mt.x; acc.y += w * mt.y;
            acc.z += w * mt.z; acc.w += w * mt.w;
        }
        half4v o;
        o[0] = (_Float16)fmaxf(dv * acc.x + bia.x, 0.f);
        o[1] = (_Float16)fmaxf(dv * acc.y + bia.y, 0.f);
        o[2] = (_Float16)fmaxf(dv * acc.z + bia.z, 0.f);
        o[3] = (_Float16)fmaxf(dv * acc.w + bia.w, 0.f);
        *(half4v*)(ob + (size_t)v * kGH + c) = o;
    }
}

// ---------------------------------------------------------------------------
// Conv2 GEMM via MFMA f16, LDS-tiled: hs = fp8(HS_SCALE * dinv ⊙ (h2 @ W2))
// BM=128, BN=128, BK=64. 4 waves (2x2); wave = 64x64.
// ---------------------------------------------------------------------------
__launch_bounds__(256)
__global__ void gemm2_mfma_kernel(const _Float16* __restrict__ A,
                                  const _Float16* __restrict__ Bt,
                                  const float* __restrict__ dinv,
                                  unsigned char* __restrict__ C) {
    __shared__ _Float16 As[128][72];
    __shared__ _Float16 Bs[128][72];

    int side = blockIdx.z;
    const _Float16* Ab = A + (size_t)side * kN * kGH;
    const float* db = dinv + (size_t)side * kN;
    unsigned char* Cb = C + (size_t)side * kN * kGH;

    int tid = threadIdx.x;
    int wave = tid >> 6, lane = tid & 63;
    int quad = lane >> 4, r = lane & 15;
    int wm = wave >> 1, wn = wave & 1;
    int row0 = blockIdx.x * 128;
    int col0 = blockIdx.y * 128;

    floatx4 acc[4][4];
    #pragma unroll
    for (int i = 0; i < 4; i++)
        #pragma unroll
        for (int j = 0; j < 4; j++) acc[i][j] = (floatx4){0.f, 0.f, 0.f, 0.f};

    for (int k0 = 0; k0 < kGH; k0 += 64) {
        #pragma unroll
        for (int u = 0; u < 4; u++) {
            int idx = tid + u * 256;
            int row = idx >> 3;
            int seg = (idx & 7) * 8;
            int gr = row0 + row;
            if (gr >= kN) gr = kN - 1;
            *(half8v*)&As[row][seg] = *(const half8v*)(Ab + (size_t)gr * kGH + k0 + seg);
            *(half8v*)&Bs[row][seg] = *(const half8v*)(Bt + (size_t)(col0 + row) * kGH + k0 + seg);
        }
        __syncthreads();
        #pragma unroll
        for (int ks = 0; ks < 2; ks++) {
            half8v af[4], bf[4];
            #pragma unroll
            for (int mt = 0; mt < 4; mt++)
                af[mt] = *(const half8v*)&As[wm * 64 + mt * 16 + r][ks * 32 + quad * 8];
            #pragma unroll
            for (int nt = 0; nt < 4; nt++)
                bf[nt] = *(const half8v*)&Bs[wn * 64 + nt * 16 + r][ks * 32 + quad * 8];
            #pragma unroll
            for (int mt = 0; mt < 4; mt++)
                #pragma unroll
                for (int nt = 0; nt < 4; nt++)
                    acc[mt][nt] = __builtin_amdgcn_mfma_f32_16x16x32_f16(af[mt], bf[nt],
                                                                         acc[mt][nt], 0, 0, 0);
        }
        __syncthreads();
    }

    #pragma unroll
    for (int mt = 0; mt < 4; mt++) {
        #pragma unroll
        for (int i = 0; i < 4; i++) {
            int grow = row0 + wm * 64 + mt * 16 + quad * 4 + i;
            if (grow >= kN) continue;
            float rsq = db[grow] * HS_SCALE;
            #pragma unroll
            for (int nt = 0; nt < 4; nt++) {
                int gcol = col0 + wn * 64 + nt * 16 + r;
                float q = acc[mt][nt][i] * rsq;
                Cb[(size_t)grow * kGH + gcol] =
                    (unsigned char)__builtin_amdgcn_cvt_pk_fp8_f32(q, q, 0, false);
            }
        }
    }
}

// ---------------------------------------------------------------------------
// Unified tail GEMM via MFMA f16 (fp32 accum): C = [relu](A @ B + bias)
// A [M,K] f16 row-major, Bt [N,K] f16. BM=BN=BK=64; 4 waves 2x2; wave=32x32.
// ---------------------------------------------------------------------------
__launch_bounds__(256)
__global__ void gemm_tail_kernel(const _Float16* __restrict__ A,
                                 const _Float16* __restrict__ Bt,
                                 void* __restrict__ Cout,
                                 int N, int K,
                                 const float* __restrict__ bias,
                                 int relu, int f32out) {
    __shared__ _Float16 As[64][72];
    __shared__ _Float16 Bs[64][72];
    int tid = threadIdx.x;
    int wave = tid >> 6, lane = tid & 63;
    int quad = lane >> 4, r = lane & 15;
    int wm = wave >> 1, wn = wave & 1;
    int row0 = blockIdx.x * 64, col0 = blockIdx.y * 64;

    floatx4 acc[2][2];
    #pragma unroll
    for (int i = 0; i < 2; i++)
        #pragma unroll
        for (int j = 0; j < 2; j++) acc[i][j] = (floatx4){0.f, 0.f, 0.f, 0.f};

    for (int k0 = 0; k0 < K; k0 += 64) {
        #pragma unroll
        for (int u = 0; u < 2; u++) {
            int idx = tid + u * 256;           // 0..511
            int row = idx >> 3;                // 0..63
            int seg = (idx & 7) * 8;           // 0..56
            *(half8v*)&As[row][seg] = *(const half8v*)(A + (size_t)(row0 + row) * K + k0 + seg);
            *(half8v*)&Bs[row][seg] = *(const half8v*)(Bt + (size_t)(col0 + row) * K + k0 + seg);
        }
        __syncthreads();
        #pragma unroll
        for (int ks = 0; ks < 2; ks++) {
            half8v af[2], bf[2];
            #pragma unroll
            for (int mt = 0; mt < 2; mt++)
                af[mt] = *(const half8v*)&As[wm * 32 + mt * 16 + r][ks * 32 + quad * 8];
            #pragma unroll
            for (int nt = 0; nt < 2; nt++)
                bf[nt] = *(const half8v*)&Bs[wn * 32 + nt * 16 + r][ks * 32 + quad * 8];
            #pragma unroll
            for (int mt = 0; mt < 2; mt++)
                #pragma unroll
                for (int nt = 0; nt < 2; nt++)
                    acc[mt][nt] = __builtin_amdgcn_mfma_f32_16x16x32_f16(af[mt], bf[nt],
                                                                         acc[mt][nt], 0, 0, 0);
        }
        __syncthreads();
    }

    #pragma unroll
    for (int mt = 0; mt < 2; mt++) {
        #pragma unroll
        for (int i = 0; i < 4; i++) {
            int grow = row0 + wm * 32 + mt * 16 + quad * 4 + i;
            #pragma unroll
            for (int nt = 0; nt < 2; nt++) {
                int gcol = col0 + wn * 32 + nt * 16 + r;
                float v = acc[mt][nt][i] + bias[gcol];
                if (relu) v = fmaxf(v, 0.f);
                if (f32out) ((float*)Cout)[(size_t)grow * N + gcol] = v;
                else ((_Float16*)Cout)[(size_t)grow * N + gcol] = (_Float16)v;
            }
        }
    }
}

// ---------------------------------------------------------------------------
// Fused conv2-aggregate + mean-pool. One block per (graph, side); 4 waves;
// wave w handles nodes start+w, start+w+4, ... (batch sorted -> contiguous).
// Per node: h4row = relu(dinv*(hs[v] + sum_s hs[s])/HS_SCALE + b2) in regs,
// accumulated into per-wave fp32 partial; LDS 4-way reduce -> pooled16.
// h4 is NEVER materialized (kills 50MB write + 51MB pool re-read).
// ---------------------------------------------------------------------------
__global__ void aggpool_kernel(const unsigned char* __restrict__ hs, const float* __restrict__ dinv,
                               const int* __restrict__ counts,
                               const unsigned short* __restrict__ col_ell,
                               const float* __restrict__ bias,
                               const int* __restrict__ batch1, const int* __restrict__ batch2,
                               _Float16* __restrict__ pooled16) {
    int side = blockIdx.y;
    int g = blockIdx.x;
    const unsigned char* hb = hs + (size_t)side * kN * kGH;
    const float* dv_ = dinv + side * kN;
    const int* deg = counts + side * kN;
    const unsigned short* ci = col_ell + (size_t)side * kN * kMD;
    const int* batch = side ? batch2 : batch1;

    // graph node range [start, end)
    int lo = 0, hi = kN;
    while (lo < hi) { int mid = (lo + hi) >> 1; if (batch[mid] < g) lo = mid + 1; else hi = mid; }
    int start = lo;
    lo = start; hi = kN;
    while (lo < hi) { int mid = (lo + hi) >> 1; if (batch[mid] < g + 1) lo = mid + 1; else hi = mid; }
    int end = lo;

    int wave = threadIdx.x >> 6;
    int lane = threadIdx.x & 63;
    int c = lane * 4;
    float4 bia = *(const float4*)(bias + c);
    float p0 = 0.f, p1 = 0.f, p2 = 0.f, p3 = 0.f;

    for (int v = start + wave; v < end; v += 4) {
        float dv = dv_[v];
        float a0 = 0.f, a1 = 0.f, a2 = 0.f, a3 = 0.f;
        acc_fp8x4(*(const unsigned int*)(hb + (size_t)v * kGH + c), a0, a1, a2, a3); // self
        int cnt = min(deg[v], kMD);
        int idxl = (lane < cnt) ? (int)ci[(size_t)v * kMD + lane] : 0;
        int j = 0;
        for (; j + 16 <= cnt; j += 16) {
            unsigned int w[16];
            #pragma unroll
            for (int u = 0; u < 16; u++)
                w[u] = *(const unsigned int*)(hb + (size_t)__shfl(idxl, j + u) * kGH + c);
            #pragma unroll
            for (int u = 0; u < 16; u++) acc_fp8x4(w[u], a0, a1, a2, a3);
        }
        for (; j + 8 <= cnt; j += 8) {
            unsigned int w[8];
            #pragma unroll
            for (int u = 0; u < 8; u++)
                w[u] = *(const unsigned int*)(hb + (size_t)__shfl(idxl, j + u) * kGH + c);
            #pragma unroll
            for (int u = 0; u < 8; u++) acc_fp8x4(w[u], a0, a1, a2, a3);
        }
        for (; j < cnt; j++)
            acc_fp8x4(*(const unsigned int*)(hb + (size_t)__shfl(idxl, j) * kGH + c),
                      a0, a1, a2, a3);
        float f = dv * HS_INV;
        p0 += fmaxf(f * a0 + bia.x, 0.f);
        p1 += fmaxf(f * a1 + bia.y, 0.f);
        p2 += fmaxf(f * a2 + bia.z, 0.f);
        p3 += fmaxf(f * a3 + bia.w, 0.f);
    }

    __shared__ float psum[4][256];
    *(float4*)&psum[wave][c] = make_float4(p0, p1, p2, p3);
    __syncthreads();
    int t = threadIdx.x;   // 256 = one column each
    if (t < 256) {
        float s = psum[0][t] + psum[1][t] + psum[2][t] + psum[3][t];
        float inv = 1.0f / fmaxf((float)(end - start), 1.0f);
        pooled16[(size_t)(side * kG + g) * kGH + t] = (_Float16)(s * inv);
    }
}

// entity gather: e16[r][k] = fp16(relu(emb[ent[r]][k])), r in [0,2G)
__global__ void egather_kernel(const float* __restrict__ emb,
                               const int* __restrict__ ent1, const int* __restrict__ ent2,
                               _Float16* __restrict__ e16) {
    int rr = blockIdx.x;
    int idx = (rr < kG) ? ent1[rr] : ent2[rr - kG];
    int k = threadIdx.x;   // 128
    e16[(size_t)rr * kEMB + k] = (_Float16)fmaxf(emb[(size_t)idx * kEMB + k], 0.f);
}

// egs prep: egs16[g][k] = fp16(relu(eg1[g][k] + eg2[g][k]))
__global__ void egsprep_kernel(const _Float16* __restrict__ gfc16,
                               const _Float16* __restrict__ ento16,
                               _Float16* __restrict__ egs16) {
    int idx = blockIdx.x * 256 + threadIdx.x;   // 0..65535
    int g = idx >> 6;                            // 0..1023
    int k8 = (idx & 63) * 8;                     // 0..504
    const _Float16* src = (k8 < kGH) ? gfc16 : ento16;
    int kk = (k8 < kGH) ? k8 : k8 - kGH;
    half8v a = *(const half8v*)(src + (size_t)g * kGH + kk);
    half8v b = *(const half8v*)(src + (size_t)(g + kG) * kGH + kk);
    half8v o;
    #pragma unroll
    for (int u = 0; u < 8; u++) o[u] = (_Float16)fmaxf((float)a[u] + (float)b[u], 0.f);
    *(half8v*)(egs16 + (size_t)g * kHID + k8) = o;
}

// ---------------------------------------------------------------------------
// Host launch
// ---------------------------------------------------------------------------
static inline char* carve(char*& p, size_t bytes) {
    char* r = p;
    p += (bytes + 255) & ~(size_t)255;
    return r;
}

extern "C" void kernel_launch(void* const* d_in, const int* in_sizes, int n_in,
                              void* d_out, int out_size, void* d_ws, size_t ws_size,
                              hipStream_t stream) {
    const int*   x1       = (const int*)d_in[0];
    const int*   ei1      = (const int*)d_in[1];
    const int*   ent1     = (const int*)d_in[2];
    const int*   batch1   = (const int*)d_in[3];
    const int*   x2       = (const int*)d_in[4];
    const int*   ei2      = (const int*)d_in[5];
    const int*   ent2     = (const int*)d_in[6];
    const int*   batch2   = (const int*)d_in[7];
    const float* atom_emb = (const float*)d_in[8];
    const float* gW1      = (const float*)d_in[9];
    const float* gb1      = (const float*)d_in[10];
    const float* gW2      = (const float*)d_in[11];
    const float* gb2      = (const float*)d_in[12];
    const float* fcW      = (const float*)d_in[13];
    const float* fcb      = (const float*)d_in[14];
    const float* ent_emb  = (const float*)d_in[15];
    const float* eW1      = (const float*)d_in[16];
    const float* eb1      = (const float*)d_in[17];
    const float* eW2      = (const float*)d_in[18];
    const float* eb2      = (const float*)d_in[19];
    const float* dW1      = (const float*)d_in[20];
    const float* db1      = (const float*)d_in[21];
    const float* dW2      = (const float*)d_in[22];
    const float* db2      = (const float*)d_in[23];
    const float* dW3      = (const float*)d_in[24];
    const float* db3      = (const float*)d_in[25];
    float* out = (float*)d_out;

    // Workspace carve (no zeroed spans needed — binp3 writes all counts).
    char* p = (char*)d_ws;
    _Float16* h2_h   = (_Float16*)carve(p, (size_t)2 * kN * kGH * 2);
    unsigned char* hs8 = (unsigned char*)carve(p, (size_t)2 * kN * kGH); // fp8 hs
    unsigned short* col_ell = (unsigned short*)carve(p, (size_t)2 * kN * kMD * 2);
    unsigned int* ebuf = (unsigned int*)carve(p, (size_t)2 * kE * 4);
    int*   poff    = (int*)  carve(p, (size_t)2 * kNBKT * 256 * 4);
    int*   btot    = (int*)  carve(p, (size_t)2 * kNBKT * 4);
    int*   bbase   = (int*)  carve(p, (size_t)2 * (kNBKT + 1) * 4);
    int*   counts  = (int*)  carve(p, (size_t)2 * kN * 4);
    float* dinv    = (float*)carve(p, (size_t)2 * kN * 4);
    int2*  xd      = (int2*) carve(p, (size_t)2 * kN * 8);
    float* M11     = (float*)carve(p, 11 * kGH * 4);
    _Float16* w2t  = (_Float16*)carve(p, (size_t)kGH * kGH * 2);
    // fp16 tail buffers
    _Float16* pooled16 = (_Float16*)carve(p, (size_t)2 * kG * kGH * 2);
    _Float16* gfc16    = (_Float16*)carve(p, (size_t)2 * kG * kGH * 2);
    _Float16* e16      = (_Float16*)carve(p, (size_t)2 * kG * kEMB * 2);
    _Float16* etmp16   = (_Float16*)carve(p, (size_t)2 * kG * kEH * 2);
    _Float16* ento16   = (_Float16*)carve(p, (size_t)2 * kG * kEH * 2);
    _Float16* egs16    = (_Float16*)carve(p, (size_t)kG * kHID * 2);
    _Float16* dh1_16   = (_Float16*)carve(p, (size_t)kG * kHID * 2);
    _Float16* dh2_16   = (_Float16*)carve(p, (size_t)kG * kHID * 2);
    // fp16 transposed tail weights
    _Float16* dW1t = (_Float16*)carve(p, (size_t)kHID * kHID * 2);
    _Float16* dW2t = (_Float16*)carve(p, (size_t)kHID * kHID * 2);
    _Float16* dW3t = (_Float16*)carve(p, (size_t)kOUT * kHID * 2);
    _Float16* fcWt = (_Float16*)carve(p, (size_t)kGH * kGH * 2);
    _Float16* eW1t = (_Float16*)carve(p, (size_t)kEH * kEMB * 2);
    _Float16* eW2t = (_Float16*)carve(p, (size_t)kEH * kEH * 2);

    // --- Graph structure via LDS binning (zero global atomics) + conv1 ---
    prep_kernel<<<267, 256, 0, stream>>>(atom_emb, gW1, gW2, M11, w2t);
    wtrans_kernel<<<2944, 256, 0, stream>>>(dW1, dW2, dW3, fcW, eW1, eW2,
                                            dW1t, dW2t, dW3t, fcWt, eW1t, eW2t);
    binp1_kernel<<<dim3(kPBLK, 2), 256, 0, stream>>>(ei1, ei2, poff);
    scanA_kernel<<<dim3(kNBKT, 2), 256, 0, stream>>>(poff, btot);
    scanB_kernel<<<2, 256, 0, stream>>>(btot, bbase);
    binp2_kernel<<<dim3(kPBLK, 2), 256, 0, stream>>>(ei1, ei2, poff, bbase, ebuf);
    binp3_kernel<<<dim3(kNBKT, 2), 256, 0, stream>>>(ebuf, bbase, col_ell, counts,
                                                     dinv, xd, x1, x2);
    conv1_combine_kernel<<<dim3(kN / 16, 2), 256, 0, stream>>>(xd, counts, col_ell,
                                                               M11, gb1, h2_h);

    // --- Conv2 GEMM (MFMA f16): hs8 = fp8(128 * dinv ⊙ (h2 @ W2)) ---
    gemm2_mfma_kernel<<<dim3((kN + 127) / 128, kGH / 128, 2), 256, 0, stream>>>(h2_h, w2t,
                                                                                dinv, hs8);
    // --- Fused aggregate + mean-pool -> pooled16 (h4 never materialized) ---
    aggpool_kernel<<<dim3(kG, 2), 256, 0, stream>>>(hs8, dinv, counts, col_ell,
                                                    gb2, batch1, batch2, pooled16);
    // --- Entity gather (fp16) ---
    egather_kernel<<<2 * kG, 128, 0, stream>>>(ent_emb, ent1, ent2, e16);

    // --- Tail GEMMs, all fp16 MFMA (fp32 accum) ---
    gemm_tail_kernel<<<dim3(2 * kG / 64, kGH / 64), 256, 0, stream>>>(
        pooled16, fcWt, gfc16, kGH, kGH, fcb, 0, 0);
    gemm_tail_kernel<<<dim3(2 * kG / 64, kEH / 64), 256, 0, stream>>>(
        e16, eW1t, etmp16, kEH, kEMB, eb1, 1, 0);
    gemm_tail_kernel<<<dim3(2 * kG / 64, kEH / 64), 256, 0, stream>>>(
        etmp16, eW2t, ento16, kEH, kEH, eb2, 1, 0);
    egsprep_kernel<<<kG * kHID / 8 / 256, 256, 0, stream>>>(gfc16, ento16, egs16);
    gemm_tail_kernel<<<dim3(kG / 64, kHID / 64), 256, 0, stream>>>(
        egs16, dW1t, dh1_16, kHID, kHID, db1, 1, 0);
    gemm_tail_kernel<<<dim3(kG / 64, kHID / 64), 256, 0, stream>>>(
        dh1_16, dW2t, dh2_16, kHID, kHID, db2, 1, 0);
    gemm_tail_kernel<<<dim3(kG / 64, kOUT / 64), 256, 0, stream>>>(
        dh2_16, dW3t, out, kOUT, kHID, db3, 0, 1);
}